// Round 10
// baseline (103.503 us; speedup 1.0000x reference)
//
#include <hip/hip_runtime.h>
#include <hip/hip_bf16.h>

#define NB   2048
#define NG   2000
#define NC   50
#define NH   256
#define NZD  32
#define NK   10
#define NP   4
#define BT   128     // rows per block
#define GS   2048
#define KP   320
#define NCH  10      // KP/32

typedef short short8  __attribute__((ext_vector_type(8)));
typedef short short4v __attribute__((ext_vector_type(4)));
typedef float f32x4   __attribute__((ext_vector_type(4)));
typedef unsigned int uint2v __attribute__((ext_vector_type(2)));

__device__ __forceinline__ unsigned short f2bf(float f) {
    union { float f; unsigned u; } v; v.f = f;
    unsigned r = v.u + 0x7fffu + ((v.u >> 16) & 1u);
    return (unsigned short)(r >> 16);
}

__device__ __forceinline__ unsigned cvt_pk_bf16(float lo, float hi) {
    unsigned r;
    asm("v_cvt_pk_bf16_f32 %0, %1, %2" : "=v"(r) : "v"(lo), "v"(hi));
    return r;
}

// async 16B global->LDS (no VGPR round-trip, counted by vmcnt, in-order)
__device__ __forceinline__ void gld16(const unsigned short* g, char* l) {
    __builtin_amdgcn_global_load_lds(
        (const __attribute__((address_space(1))) unsigned int*)g,
        (__attribute__((address_space(3))) unsigned int*)l, 16, 0, 0);
}

// ---------------- deterministic ordered compaction of M --------------------
__global__ void build_gidx(const float* __restrict__ M, int* __restrict__ gidx,
                           int* __restrict__ gcnt) {
    int c = blockIdx.x;
    int t = threadIdx.x;
    __shared__ int wcnt[4];
    __shared__ int base;
    if (t == 0) base = 0;
    __syncthreads();
    for (int g0 = 0; g0 < NG; g0 += 256) {
        int g = g0 + t;
        bool a = (g < NG) && (M[c * NG + g] != 0.0f);
        unsigned long long mask = __ballot(a);
        int lane = t & 63;
        int w = t >> 6;
        if (lane == 0) wcnt[w] = __popcll(mask);
        int pre = __popcll(mask & ((1ull << lane) - 1ull));
        __syncthreads();
        int woff = base;
        for (int i = 0; i < w; ++i) woff += wcnt[i];
        if (a) gidx[c * GS + woff + pre] = g;
        int tot = wcnt[0] + wcnt[1] + wcnt[2] + wcnt[3];
        __syncthreads();
        if (t == 0) base += tot;
        __syncthreads();
    }
    if (t == 0) gcnt[c] = base;
}

// ---------------- merged prep kernel ---------------------------------------
// blocks [0,1024): X transpose; [1024,1524): w1s; [1524,1532): w2s; [1532,1582): cwb
// w1s/w2s: fragment-order [col][32k], 16B unit q stored at q ^ ((col>>1)&3)
// cwb: [o][256h], 16B unit u stored at u ^ (o&7)
__global__ void prep_all(const float* __restrict__ X, const float* __restrict__ W1,
                         const float* __restrict__ W2, const float* __restrict__ cw,
                         const int* __restrict__ gidx, const int* __restrict__ gcnt,
                         unsigned short* __restrict__ xt, unsigned short* __restrict__ w1s,
                         unsigned short* __restrict__ w2s, unsigned short* __restrict__ cwb) {
    __shared__ float tile[64][65];
    const int bx = blockIdx.x;
    const int t  = threadIdx.x;
    if (bx < 1024) {                       // ---- xt: X^T to bf16, gene-major
        int gb = bx & 31, bb = bx >> 5;
        int tx = t & 63, tq = t >> 6;
        #pragma unroll
        for (int i = 0; i < 16; ++i) {
            int r = tq * 16 + i;
            int gene = gb * 64 + tx;
            tile[r][tx] = (gene < NG) ? X[(size_t)(bb * 64 + r) * NG + gene] : 0.f;
        }
        __syncthreads();
        #pragma unroll
        for (int i = 0; i < 16; ++i) {
            int gl = tq * 16 + i;
            int gene = gb * 64 + gl;
            if (gene < NG)
                xt[(size_t)gene * NB + bb * 64 + tx] = f2bf(tile[tx][gl]);
        }
    } else if (bx < 1524) {                // ---- w1s: gathered W1
        int idx = bx - 1024;
        int ch = idx % NCH, c = idx / NCH;
        int col = t;
        int cnt = gcnt[c]; if (cnt > KP) cnt = KP;
        unsigned short v[32];
        #pragma unroll
        for (int kin = 0; kin < 32; ++kin) {
            int k = ch * 32 + kin;
            float x = 0.f;
            if (k < cnt) {
                int g = gidx[c * GS + k];
                x = W1[(size_t)g * NH + col];
            }
            v[kin] = f2bf(x);
        }
        unsigned short* dst = w1s + (((size_t)(c * NCH + ch)) * 256 + col) * 32;
        #pragma unroll
        for (int q = 0; q < 4; ++q) {
            short8 v8;
            #pragma unroll
            for (int i = 0; i < 8; ++i) v8[i] = (short)v[q * 8 + i];
            *(short8*)(dst + (q ^ ((col >> 1) & 3)) * 8) = v8;
        }
    } else if (bx < 1532) {                // ---- w2s: W2^T chunks
        int ch = bx - 1524;
        int col = t;
        unsigned short v[32];
        #pragma unroll
        for (int kin = 0; kin < 32; ++kin)
            v[kin] = f2bf(W2[(size_t)(ch * 32 + kin) * NH + col]);
        unsigned short* dst = w2s + ((size_t)ch * 256 + col) * 32;
        #pragma unroll
        for (int q = 0; q < 4; ++q) {
            short8 v8;
            #pragma unroll
            for (int i = 0; i < 8; ++i) v8[i] = (short)v[q * 8 + i];
            *(short8*)(dst + (q ^ ((col >> 1) & 3)) * 8) = v8;
        }
    } else {                               // ---- cwb: cw -> bf16 [o][256], swizzled
        int c = bx - 1532;
        int o = t >> 3, seg = t & 7;
        #pragma unroll
        for (int blk = 0; blk < 4; ++blk) {
            int u = seg * 4 + blk;         // 16B unit (8 h's)
            short8 v8;
            #pragma unroll
            for (int i = 0; i < 8; ++i)
                v8[i] = (short)f2bf(cw[((size_t)c * NZD + o) * NH + u * 8 + i]);
            *(short8*)(cwb + (size_t)c * 8192 + o * 256 + (u ^ (o & 7)) * 8) = v8;
        }
    }
}

// ---------------- main fused kernel -----------------------------------------
// 512 threads = 8 waves; 1 block/CU (128 KB LDS). Wave tile 64 rows x 64 cols.
// LDS:
//   [0, 81920)      : X bf16 [128][320] swizzled (stage A); post-A:
//                     [0,65536) H bf16 [128][256] swizzled, [65536,73728) protos
//   [81920,131072)  : 3 x 16 KB staging buffers (SB0..SB2); post-B:
//                     SB(18%3)=SB0 holds cw; SZ f32 [128][36] at SB1 (18432 B)
#define PP_OFF   65536
#define SB_BASE  81920
#define SZ_OFF   98304
#define LDS_BYTES 131072

__global__ __launch_bounds__(512, 2) void fused_mfma9(
    const unsigned short* __restrict__ xt,
    const unsigned short* __restrict__ w1s,
    const unsigned short* __restrict__ w2s,
    const unsigned short* __restrict__ cwb,
    const float* __restrict__ b1, const float* __restrict__ b2,
    const float* __restrict__ cb, const float* __restrict__ protos,
    const float* __restrict__ logvar, const float* __restrict__ c_bias,
    const int* __restrict__ gidx, const int* __restrict__ gcnt,
    float* __restrict__ out_cl)
{
    extern __shared__ char sm[];
    const int t  = threadIdx.x;
    const int l  = t & 63;
    const int w  = t >> 6;      // 0..7
    const int lr = l & 15;
    const int lg = l >> 4;      // 0..3
    const int wb = w >> 2;      // 0..1: row half (64 rows)
    const int wh = w & 3;       // 0..3: col block (64 cols)
    const int row0 = blockIdx.x * BT;
    const int c    = blockIdx.y;
    int cnt = gcnt[c]; if (cnt > KP) cnt = KP;

    auto Hb = [&](int r, int k) -> char* {   // H bf16 [128][256] swizzled
        return sm + r * 512 + ((((k >> 3) ^ (r & 7)) << 4) | ((k & 7) << 1));
    };
    auto XLb = [&](int r, int k) -> char* {  // X bf16 [128][320] swizzled
        return sm + r * 640 + ((((k >> 3) ^ (r & 7)) << 4) | ((k & 7) << 1));
    };
    auto gsrc_for = [&](int i) -> const unsigned short* {   // 18-chunk chain + cw
        if (i < NCH)     return w1s + ((size_t)(c * NCH + i)) * 8192;
        if (i < NCH + 8) return w2s + (size_t)(i - NCH) * 8192;
        return cwb + (size_t)c * 8192;
    };
    auto stage_w = [&](int i) {              // 16 KB chunk -> SB(i%3), 2 vmem/thread
        const unsigned short* g = gsrc_for(i);
        char* base = sm + SB_BASE + (i % 3) * 16384;
        gld16(g + t * 8,        base + t * 16);
        gld16(g + 4096 + t * 8, base + 8192 + t * 16);
    };
    auto aread = [&](int sb, int col, int unit) -> short8 { // staged W frag read
        return *(const short8*)(sm + SB_BASE + sb * 16384 + col * 64 +
                                ((unit ^ ((col >> 1) & 3)) << 4));
    };

    // ---- prologue: stages 0,1 first (oldest in vmcnt queue), bias preload ----
    stage_w(0);
    stage_w(1);
    f32x4 b1v[4], b2v[4];
    #pragma unroll
    for (int mm = 0; mm < 4; ++mm) {
        int k0 = wh * 64 + mm * 16 + lg * 4;
        b1v[mm] = *(const f32x4*)(b1 + k0);
        b2v[mm] = *(const f32x4*)(b2 + k0);
    }

    // ---- phase 0: gather ALL of Xc (128 rows x 320 genes) into LDS ----------
    {
        const int pr = t & 31;          // gene pair within 64-gene group
        const int rq = t >> 5;          // 0..15 (8 rows each)
        #pragma unroll
        for (int i = 0; i < 5; ++i) {
            const int k0 = i * 64 + pr * 2;
            short8 x0 = short8{0,0,0,0,0,0,0,0}, x1 = short8{0,0,0,0,0,0,0,0};
            if (k0 < cnt) {
                int g = gidx[c * GS + k0];
                x0 = *(const short8*)(xt + (size_t)g * NB + row0 + rq * 8);
            }
            if (k0 + 1 < cnt) {
                int g = gidx[c * GS + k0 + 1];
                x1 = *(const short8*)(xt + (size_t)g * NB + row0 + rq * 8);
            }
            #pragma unroll
            for (int j = 0; j < 8; ++j) {
                int r = rq * 8 + j;
                unsigned pk = (unsigned)(unsigned short)x0[j] |
                              ((unsigned)(unsigned short)x1[j] << 16);
                *(unsigned*)XLb(r, k0) = pk;
            }
        }
    }
    asm volatile("s_waitcnt lgkmcnt(0)" ::: "memory");
    __builtin_amdgcn_s_barrier();
    asm volatile("" ::: "memory");

    // ---- stage A: h1 = leaky(Xc @ W1c + b1); depth-2 counted-vmcnt pipe -----
    f32x4 acc[4][4];
    #pragma unroll
    for (int nn = 0; nn < 4; ++nn)
        #pragma unroll
        for (int mm = 0; mm < 4; ++mm) acc[nn][mm] = f32x4{0.f, 0.f, 0.f, 0.f};

    for (int i = 0; i < NCH; ++i) {
        asm volatile("s_waitcnt vmcnt(2)" ::: "memory");  // stage(i) landed
        __builtin_amdgcn_s_barrier();
        asm volatile("" ::: "memory");
        stage_w(i + 2);                                   // i+2 <= 11 always valid
        const int sb = i % 3;
        short8 a[4], b[4];
        #pragma unroll
        for (int mm = 0; mm < 4; ++mm)
            a[mm] = aread(sb, wh * 64 + mm * 16 + lr, lg);
        #pragma unroll
        for (int nn = 0; nn < 4; ++nn)
            b[nn] = *(const short8*)XLb(wb * 64 + nn * 16 + lr, i * 32 + lg * 8);
        #pragma unroll
        for (int nn = 0; nn < 4; ++nn)
            #pragma unroll
            for (int mm = 0; mm < 4; ++mm)
                acc[nn][mm] = __builtin_amdgcn_mfma_f32_16x16x32_bf16(a[mm], b[nn], acc[nn][mm], 0, 0, 0);
    }

    // ---- epilogue A: raw barriers (stages 10,11 stay in flight) -------------
    __builtin_amdgcn_s_barrier();            // all X reads consumed
    asm volatile("" ::: "memory");
    #pragma unroll
    for (int mm = 0; mm < 4; ++mm) {
        int k0 = wh * 64 + mm * 16 + lg * 4;
        #pragma unroll
        for (int nn = 0; nn < 4; ++nn) {
            int r = wb * 64 + nn * 16 + lr;
            float v0 = acc[nn][mm][0] + b1v[mm][0]; v0 = (v0 >= 0.f) ? v0 : 0.01f * v0;
            float v1 = acc[nn][mm][1] + b1v[mm][1]; v1 = (v1 >= 0.f) ? v1 : 0.01f * v1;
            float v2 = acc[nn][mm][2] + b1v[mm][2]; v2 = (v2 >= 0.f) ? v2 : 0.01f * v2;
            float v3 = acc[nn][mm][3] + b1v[mm][3]; v3 = (v3 >= 0.f) ? v3 : 0.01f * v3;
            uint2v pk;
            pk[0] = cvt_pk_bf16(v0, v1);
            pk[1] = cvt_pk_bf16(v2, v3);
            *(uint2v*)Hb(r, k0) = pk;
        }
    }
    asm volatile("s_waitcnt lgkmcnt(0)" ::: "memory");
    __builtin_amdgcn_s_barrier();
    asm volatile("" ::: "memory");

    // ---- stage B: h2 = leaky(h1 @ W2 + b2); same pipe ------------------------
    f32x4 acc2[4][4];
    #pragma unroll
    for (int nn = 0; nn < 4; ++nn)
        #pragma unroll
        for (int mm = 0; mm < 4; ++mm) acc2[nn][mm] = f32x4{0.f, 0.f, 0.f, 0.f};
    for (int i = NCH; i < NCH + 8; ++i) {
        asm volatile("s_waitcnt vmcnt(2)" ::: "memory");
        __builtin_amdgcn_s_barrier();
        asm volatile("" ::: "memory");
        if (i + 2 <= NCH + 8) stage_w(i + 2);             // last stage: 18 = cw
        const int sb = i % 3;
        const int ch = i - NCH;
        short8 a[4], b[4];
        #pragma unroll
        for (int mm = 0; mm < 4; ++mm)
            a[mm] = aread(sb, wh * 64 + mm * 16 + lr, lg);
        #pragma unroll
        for (int nn = 0; nn < 4; ++nn)
            b[nn] = *(const short8*)Hb(wb * 64 + nn * 16 + lr, ch * 32 + lg * 8);
        #pragma unroll
        for (int nn = 0; nn < 4; ++nn)
            #pragma unroll
            for (int mm = 0; mm < 4; ++mm)
                acc2[nn][mm] = __builtin_amdgcn_mfma_f32_16x16x32_bf16(a[mm], b[nn], acc2[nn][mm], 0, 0, 0);
    }

    // ---- epilogue B: h2 -> H (overwrite) + protos/i2e/cbias ------------------
    __builtin_amdgcn_s_barrier();            // all H(h1) reads consumed
    asm volatile("" ::: "memory");
    {
        #pragma unroll
        for (int mm = 0; mm < 4; ++mm) {
            int k0 = wh * 64 + mm * 16 + lg * 4;
            #pragma unroll
            for (int nn = 0; nn < 4; ++nn) {
                int r = wb * 64 + nn * 16 + lr;
                float v0 = acc2[nn][mm][0] + b2v[mm][0]; v0 = (v0 >= 0.f) ? v0 : 0.01f * v0;
                float v1 = acc2[nn][mm][1] + b2v[mm][1]; v1 = (v1 >= 0.f) ? v1 : 0.01f * v1;
                float v2 = acc2[nn][mm][2] + b2v[mm][2]; v2 = (v2 >= 0.f) ? v2 : 0.01f * v2;
                float v3 = acc2[nn][mm][3] + b2v[mm][3]; v3 = (v3 >= 0.f) ? v3 : 0.01f * v3;
                uint2v pk;
                pk[0] = cvt_pk_bf16(v0, v1);
                pk[1] = cvt_pk_bf16(v2, v3);
                *(uint2v*)Hb(r, k0) = pk;
            }
        }
        float* pp = (float*)(sm + PP_OFF);
        for (int i = t; i < NK * NP * NZD; i += 512)
            pp[(i >> 5) * 36 + (i & 31)] = protos[(size_t)c * (NK * NP * NZD) + i];
        if (t < NK * NP) pp[1440 + t] = 0.5f * expf(-logvar[c * (NK * NP) + t]);
        if (t < NK)      pp[1480 + t] = c_bias[c * NK + t];
    }
    asm volatile("s_waitcnt vmcnt(0) lgkmcnt(0)" ::: "memory");  // cw stage + writes done
    __builtin_amdgcn_s_barrier();
    asm volatile("" ::: "memory");

    // ---- stage C: Z = h2 @ cw^T + cb (8 waves x 16 rows, cw in SB0) ----------
    {
        const int row = w * 16 + lr;
        f32x4 az[2];
        az[0] = f32x4{0.f, 0.f, 0.f, 0.f};
        az[1] = f32x4{0.f, 0.f, 0.f, 0.f};
        #pragma unroll
        for (int ch = 0; ch < 8; ++ch) {
            short8 bfr = *(const short8*)Hb(row, ch * 32 + lg * 8);
            #pragma unroll
            for (int ot = 0; ot < 2; ++ot) {
                int o = ot * 16 + lr;
                short8 afr = *(const short8*)(sm + SB_BASE + o * 512 +
                                              ((((ch << 2) + lg) ^ (o & 7)) << 4));
                az[ot] = __builtin_amdgcn_mfma_f32_16x16x32_bf16(afr, bfr, az[ot], 0, 0, 0);
            }
        }
        float* SZ = (float*)(sm + SZ_OFF);
        #pragma unroll
        for (int ot = 0; ot < 2; ++ot) {
            f32x4 cb4 = *(const f32x4*)(cb + c * NZD + ot * 16 + lg * 4);
            #pragma unroll
            for (int i = 0; i < 4; ++i)
                SZ[row * 36 + ot * 16 + lg * 4 + i] = az[ot][i] + cb4[i];
        }
    }
    asm volatile("s_waitcnt lgkmcnt(0)" ::: "memory");
    __builtin_amdgcn_s_barrier();
    asm volatile("" ::: "memory");

    // ---- stage D: prototype distances -> c_logits ----------------------------
    {
        const float* SZ  = (const float*)(sm + SZ_OFF);
        const float* pp  = (const float*)(sm + PP_OFF);
        const float* i2e = pp + 1440;
        const float* cbs = pp + 1480;
        const int rloc = w * 16 + lr;
        f32x4 z[8];
        #pragma unroll
        for (int j = 0; j < 8; ++j)
            z[j] = *(const f32x4*)(SZ + rloc * 36 + j * 4);
        #pragma unroll
        for (int kk = 0; kk < NK; ++kk) {
            int kp = kk * NP + lg;       // lg == p
            f32x4 d = f32x4{0.f, 0.f, 0.f, 0.f};
            #pragma unroll
            for (int j = 0; j < 8; ++j) {
                f32x4 p = *(const f32x4*)(pp + kp * 36 + j * 4);
                f32x4 df = z[j] - p;
                d += df * df;
            }
            float sc = ((d[0] + d[1]) + (d[2] + d[3])) * i2e[kp];
            sc = fminf(sc, __shfl_xor(sc, 16));
            sc = fminf(sc, __shfl_xor(sc, 32));
            if (lg == 0)
                out_cl[((size_t)(row0 + rloc) * NC + c) * NK + kk] = cbs[kk] - sc;
        }
    }
}

// ---------------- fallback (round-1 fp32 path, known-good) -----------------
__global__ __launch_bounds__(256, 1) void fused_main(
    const float* __restrict__ X,  const float* __restrict__ W1,
    const float* __restrict__ b1, const float* __restrict__ W2,
    const float* __restrict__ b2, const float* __restrict__ cw,
    const float* __restrict__ cb, const float* __restrict__ protos,
    const float* __restrict__ logvar, const float* __restrict__ c_bias,
    const int* __restrict__ gidx, const int* __restrict__ gcnt,
    float* __restrict__ out_cl)
{
    extern __shared__ float smemf[];
    float (*sh_big)[258] = (float (*)[258])smemf;
    float (*sh_w)[258]   = (float (*)[258])(smemf + 16512);
    float (*sh_x)[33]    = (float (*)[33])(smemf + 16512 + 8256);
    int*  sh_gid         = (int*)(smemf + 16512 + 8256 + 2112);

    const int t   = threadIdx.x;
    const int tx  = t & 15;
    const int ty  = t >> 4;
    const int row0 = blockIdx.x * 64;
    const int c    = blockIdx.y;

    float acc[4][16];
    #pragma unroll
    for (int i = 0; i < 4; ++i)
        #pragma unroll
        for (int l = 0; l < 16; ++l) acc[i][l] = 0.f;

    const int cnt = gcnt[c];
    const int nch = (cnt + 31) >> 5;
    for (int ch = 0; ch < nch; ++ch) {
        __syncthreads();
        if (t < 32) {
            int gi = ch * 32 + t;
            sh_gid[t] = (gi < cnt) ? gidx[c * GS + gi] : -1;
        }
        __syncthreads();
        #pragma unroll 4
        for (int jj = 0; jj < 32; ++jj) {
            int g = sh_gid[jj];
            sh_w[jj][t] = (g >= 0) ? W1[g * NH + t] : 0.f;
        }
        {
            int j  = t & 31;
            int rb2 = (t >> 5) * 8;
            int g  = sh_gid[j];
            #pragma unroll
            for (int ii = 0; ii < 8; ++ii)
                sh_x[rb2 + ii][j] = (g >= 0) ? X[(size_t)(row0 + rb2 + ii) * NG + g] : 0.f;
        }
        __syncthreads();
        #pragma unroll 8
        for (int j = 0; j < 32; ++j) {
            float xv[4];
            #pragma unroll
            for (int i = 0; i < 4; ++i) xv[i] = sh_x[ty * 4 + i][j];
            #pragma unroll
            for (int l = 0; l < 16; ++l) {
                float wv = sh_w[j][l * 16 + tx];
                #pragma unroll
                for (int i = 0; i < 4; ++i) acc[i][l] = fmaf(xv[i], wv, acc[i][l]);
            }
        }
    }
    #pragma unroll
    for (int i = 0; i < 4; ++i)
        #pragma unroll
        for (int l = 0; l < 16; ++l) {
            int col = l * 16 + tx;
            float v = acc[i][l] + b1[col];
            sh_big[ty * 4 + i][col] = (v >= 0.f) ? v : 0.01f * v;
        }

    float acc2[4][16];
    #pragma unroll
    for (int i = 0; i < 4; ++i)
        #pragma unroll
        for (int l = 0; l < 16; ++l) acc2[i][l] = 0.f;
    for (int ch = 0; ch < NH / 32; ++ch) {
        __syncthreads();
        #pragma unroll 4
        for (int jj = 0; jj < 32; ++jj)
            sh_w[jj][t] = W2[(size_t)(ch * 32 + jj) * NH + t];
        __syncthreads();
        #pragma unroll 8
        for (int j = 0; j < 32; ++j) {
            float xv[4];
            #pragma unroll
            for (int i = 0; i < 4; ++i) xv[i] = sh_big[ty * 4 + i][ch * 32 + j];
            #pragma unroll
            for (int l = 0; l < 16; ++l) {
                float wv = sh_w[j][l * 16 + tx];
                #pragma unroll
                for (int i = 0; i < 4; ++i) acc2[i][l] = fmaf(xv[i], wv, acc2[i][l]);
            }
        }
    }
    __syncthreads();
    #pragma unroll
    for (int i = 0; i < 4; ++i)
        #pragma unroll
        for (int l = 0; l < 16; ++l) {
            int col = l * 16 + tx;
            float v = acc2[i][l] + b2[col];
            sh_big[ty * 4 + i][col] = (v >= 0.f) ? v : 0.01f * v;
        }
    #pragma unroll 4
    for (int o = 0; o < NZD; ++o)
        sh_w[o][t] = cw[((size_t)c * NZD + o) * NH + t];
    __syncthreads();
    {
        int o  = t & 31;
        int rg = t >> 5;
        float cbv = cb[c * NZD + o];
        float zv[8];
        #pragma unroll
        for (int i = 0; i < 8; ++i) zv[i] = cbv;
        for (int h = 0; h < NH; ++h) {
            float wv = sh_w[o][h];
            #pragma unroll
            for (int i = 0; i < 8; ++i)
                zv[i] = fmaf(sh_big[rg * 8 + i][h], wv, zv[i]);
        }
        #pragma unroll
        for (int i = 0; i < 8; ++i) sh_x[rg * 8 + i][o] = zv[i];
    }
    __syncthreads();
    float* proto_s = &sh_w[0][0];
    float* i2e_s   = proto_s + NK * NP * NZD;
    float* cbias_s = i2e_s + NK * NP;
    for (int i = t; i < NK * NP * NZD; i += 256)
        proto_s[i] = protos[(size_t)c * NK * NP * NZD + i];
    if (t < NK * NP) i2e_s[t] = 0.5f * expf(-logvar[c * NK * NP + t]);
    if (t < NK)      cbias_s[t] = c_bias[c * NK + t];
    __syncthreads();
    for (int task = t; task < 64 * NK; task += 256) {
        int r = task / NK;
        int k = task - r * NK;
        float best = 3.4e38f;
        #pragma unroll
        for (int p = 0; p < NP; ++p) {
            float d2 = 0.f;
            const float* ppr = proto_s + (k * NP + p) * NZD;
            #pragma unroll
            for (int o = 0; o < NZD; ++o) {
                float dv = sh_x[r][o] - ppr[o];
                d2 = fmaf(dv, dv, d2);
            }
            float sc = d2 * i2e_s[k * NP + p];
            best = fminf(best, sc);
        }
        out_cl[((size_t)(row0 + r) * NC + c) * NK + k] = cbias_s[k] - best;
    }
}

// ---------------- logits reduce ---------------------------------------------
__global__ void reduce_logits(const float* __restrict__ cl,
                              const float* __restrict__ importance,
                              const float* __restrict__ bias,
                              float* __restrict__ out) {
    int idx = blockIdx.x * blockDim.x + threadIdx.x;
    if (idx >= NB * NK) return;
    int b = idx / NK;
    int k = idx - b * NK;
    float s = 0.f;
    for (int c = 0; c < NC; ++c) {
        float imp = fabsf(importance[c]);
        s += expf(cl[((size_t)b * NC + c) * NK + k]) * imp + 1e-16f;
    }
    out[idx] = logf(s) + bias[k];
}

extern "C" void kernel_launch(void* const* d_in, const int* in_sizes, int n_in,
                              void* d_out, int out_size, void* d_ws, size_t ws_size,
                              hipStream_t stream) {
    const float* X      = (const float*)d_in[0];
    const float* M      = (const float*)d_in[1];
    const float* W1     = (const float*)d_in[2];
    const float* b1     = (const float*)d_in[3];
    const float* W2     = (const float*)d_in[4];
    const float* b2     = (const float*)d_in[5];
    const float* cw     = (const float*)d_in[6];
    const float* cb     = (const float*)d_in[7];
    const float* protos = (const float*)d_in[8];
    const float* logvar = (const float*)d_in[9];
    const float* c_bias = (const float*)d_in[10];
    const float* bias   = (const float*)d_in[11];
    const float* imp    = (const float*)d_in[12];

    float* out_logits = (float*)d_out;
    float* out_cl     = out_logits + NB * NK;

    // workspace layout (bytes)
    const size_t o_gcnt = (size_t)NC * GS * 4;
    const size_t o_w1s  = o_gcnt + 256;
    const size_t o_w2s  = o_w1s + (size_t)NC * NCH * 256 * 32 * 2;
    const size_t o_cwb  = o_w2s + (size_t)8 * 256 * 32 * 2;
    const size_t o_xt   = o_cwb + (size_t)NC * 32 * 256 * 2;
    const size_t need   = o_xt + (size_t)NG * NB * 2;

    int* gidx = (int*)d_ws;
    int* gcnt = (int*)((char*)d_ws + o_gcnt);
    unsigned short* w1s = (unsigned short*)((char*)d_ws + o_w1s);
    unsigned short* w2s = (unsigned short*)((char*)d_ws + o_w2s);
    unsigned short* cwb = (unsigned short*)((char*)d_ws + o_cwb);
    unsigned short* xt  = (unsigned short*)((char*)d_ws + o_xt);

    build_gidx<<<NC, 256, 0, stream>>>(M, gidx, gcnt);

    if (ws_size >= need) {
        prep_all<<<1582, 256, 0, stream>>>(X, W1, W2, cw, gidx, gcnt, xt, w1s, w2s, cwb);
        fused_mfma9<<<dim3(NB / BT, NC), 512, LDS_BYTES, stream>>>(
            xt, w1s, w2s, cwb, b1, b2, cb, protos, logvar, c_bias, gidx, gcnt, out_cl);
    } else {
        size_t smem = (size_t)(16512 + 8256 + 2112) * 4 + 32 * 4;
        fused_main<<<dim3(NB / 64, NC), 256, smem, stream>>>(
            X, W1, b1, W2, b2, cw, cb, protos, logvar, c_bias, gidx, gcnt, out_cl);
    }
    reduce_logits<<<(NB * NK + 255) / 256, 256, 0, stream>>>(out_cl, imp, bias, out_logits);
}

// Round 11
// 87.300 us; speedup vs baseline: 1.1856x; 1.1856x over previous
//
#include <hip/hip_runtime.h>
#include <hip/hip_bf16.h>

#define NB   2048
#define NG   2000
#define NC   50
#define NH   256
#define NZD  32
#define NK   10
#define NP   4
#define BT   64
#define GS   2048
#define KP   320
#define NCH  10      // KP/32

typedef short short8  __attribute__((ext_vector_type(8)));
typedef short short4v __attribute__((ext_vector_type(4)));
typedef float f32x4   __attribute__((ext_vector_type(4)));
typedef unsigned int uint2v __attribute__((ext_vector_type(2)));

__device__ __forceinline__ unsigned short f2bf(float f) {
    union { float f; unsigned u; } v; v.f = f;
    unsigned r = v.u + 0x7fffu + ((v.u >> 16) & 1u);
    return (unsigned short)(r >> 16);
}

__device__ __forceinline__ unsigned cvt_pk_bf16(float lo, float hi) {
    unsigned r;
    asm("v_cvt_pk_bf16_f32 %0, %1, %2" : "=v"(r) : "v"(lo), "v"(hi));
    return r;
}

// async 16B global->LDS (no VGPR round-trip, counted by vmcnt)
__device__ __forceinline__ void gld16(const unsigned short* g, char* l) {
    __builtin_amdgcn_global_load_lds(
        (const __attribute__((address_space(1))) unsigned int*)g,
        (__attribute__((address_space(3))) unsigned int*)l, 16, 0, 0);
}

// ---------------- deterministic ordered compaction of M (1024 thr) ---------
__global__ void build_gidx(const float* __restrict__ M, int* __restrict__ gidx,
                           int* __restrict__ gcnt) {
    int c = blockIdx.x;
    int t = threadIdx.x;
    __shared__ int wcnt[16];
    __shared__ int base;
    if (t == 0) base = 0;
    __syncthreads();
    for (int g0 = 0; g0 < NG; g0 += 1024) {
        int g = g0 + t;
        bool a = (g < NG) && (M[c * NG + g] != 0.0f);
        unsigned long long mask = __ballot(a);
        int lane = t & 63;
        int w = t >> 6;
        if (lane == 0) wcnt[w] = __popcll(mask);
        int pre = __popcll(mask & ((1ull << lane) - 1ull));
        __syncthreads();
        int woff = base;
        for (int i = 0; i < w; ++i) woff += wcnt[i];
        if (a) gidx[c * GS + woff + pre] = g;
        int tot = 0;
        #pragma unroll
        for (int i = 0; i < 16; ++i) tot += wcnt[i];
        __syncthreads();
        if (t == 0) base += tot;
        __syncthreads();
    }
    if (t == 0) gcnt[c] = base;
}

// ---------------- merged prep kernel ---------------------------------------
// blocks [0,1024): X transpose; [1024,1524): w1s; [1524,1532): w2s; [1532,1582): cwb
// w1s/w2s: fragment-order [col][32k], 16B unit q stored at q ^ ((col>>1)&3)
// cwb: [o][256h], 16B unit u stored at u ^ (o&7)
__global__ void prep_all(const float* __restrict__ X, const float* __restrict__ W1,
                         const float* __restrict__ W2, const float* __restrict__ cw,
                         const int* __restrict__ gidx, const int* __restrict__ gcnt,
                         unsigned short* __restrict__ xt, unsigned short* __restrict__ w1s,
                         unsigned short* __restrict__ w2s, unsigned short* __restrict__ cwb) {
    __shared__ float tile[64][65];
    const int bx = blockIdx.x;
    const int t  = threadIdx.x;
    if (bx < 1024) {                       // ---- xt: X^T to bf16, gene-major
        int gb = bx & 31, bb = bx >> 5;
        int tx = t & 63, tq = t >> 6;
        #pragma unroll
        for (int i = 0; i < 16; ++i) {
            int r = tq * 16 + i;
            int gene = gb * 64 + tx;
            tile[r][tx] = (gene < NG) ? X[(size_t)(bb * 64 + r) * NG + gene] : 0.f;
        }
        __syncthreads();
        #pragma unroll
        for (int i = 0; i < 16; ++i) {
            int gl = tq * 16 + i;
            int gene = gb * 64 + gl;
            if (gene < NG)
                xt[(size_t)gene * NB + bb * 64 + tx] = f2bf(tile[tx][gl]);
        }
    } else if (bx < 1524) {                // ---- w1s: gathered W1
        int idx = bx - 1024;
        int ch = idx % NCH, c = idx / NCH;
        int col = t;
        int cnt = gcnt[c]; if (cnt > KP) cnt = KP;
        unsigned short v[32];
        #pragma unroll
        for (int kin = 0; kin < 32; ++kin) {
            int k = ch * 32 + kin;
            float x = 0.f;
            if (k < cnt) {
                int g = gidx[c * GS + k];
                x = W1[(size_t)g * NH + col];
            }
            v[kin] = f2bf(x);
        }
        unsigned short* dst = w1s + (((size_t)(c * NCH + ch)) * 256 + col) * 32;
        #pragma unroll
        for (int q = 0; q < 4; ++q) {
            short8 v8;
            #pragma unroll
            for (int i = 0; i < 8; ++i) v8[i] = (short)v[q * 8 + i];
            *(short8*)(dst + (q ^ ((col >> 1) & 3)) * 8) = v8;
        }
    } else if (bx < 1532) {                // ---- w2s: W2^T chunks
        int ch = bx - 1524;
        int col = t;
        unsigned short v[32];
        #pragma unroll
        for (int kin = 0; kin < 32; ++kin)
            v[kin] = f2bf(W2[(size_t)(ch * 32 + kin) * NH + col]);
        unsigned short* dst = w2s + ((size_t)ch * 256 + col) * 32;
        #pragma unroll
        for (int q = 0; q < 4; ++q) {
            short8 v8;
            #pragma unroll
            for (int i = 0; i < 8; ++i) v8[i] = (short)v[q * 8 + i];
            *(short8*)(dst + (q ^ ((col >> 1) & 3)) * 8) = v8;
        }
    } else {                               // ---- cwb: cw -> bf16 [o][256], swizzled
        int c = bx - 1532;
        int o = t >> 3, seg = t & 7;
        #pragma unroll
        for (int blk = 0; blk < 4; ++blk) {
            int u = seg * 4 + blk;         // 16B unit (8 h's)
            short8 v8;
            #pragma unroll
            for (int i = 0; i < 8; ++i)
                v8[i] = (short)f2bf(cw[((size_t)c * NZD + o) * NH + u * 8 + i]);
            *(short8*)(cwb + (size_t)c * 8192 + o * 256 + (u ^ (o & 7)) * 8) = v8;
        }
    }
}

// ---------------- main fused kernel -----------------------------------------
// LDS (73728 B, 2 blocks/CU):
//   [0, 40960)      : X bf16 [64][320] swizzled (stage A); post-A:
//                     [0,32768) H bf16 [64][256] swizzled, [32768,40960) protos
//   [40960, 57344)  : W1 staging buf0 (16 KB) — later SZ f32 [64][36]
//   [57344, 73728)  : W1 staging buf1 (16 KB)
#define PP_OFF   32768
#define WB0      40960
#define WB1      57344
#define LDS_BYTES 73728

__global__ __launch_bounds__(512, 4) void fused_mfma10(
    const unsigned short* __restrict__ xt,
    const unsigned short* __restrict__ w1s,
    const unsigned short* __restrict__ w2s,
    const unsigned short* __restrict__ cwb,
    const float* __restrict__ b1, const float* __restrict__ b2,
    const float* __restrict__ cb, const float* __restrict__ protos,
    const float* __restrict__ logvar, const float* __restrict__ c_bias,
    const int* __restrict__ gidx, const int* __restrict__ gcnt,
    float* __restrict__ out_cl)
{
    extern __shared__ char sm[];
    const int t  = threadIdx.x;
    const int l  = t & 63;
    const int w  = t >> 6;      // 0..7
    const int lr = l & 15;
    const int lg = l >> 4;      // 0..3
    const int wb = w >> 2;      // 0..1: row block (32 rows)
    const int wh = w & 3;       // 0..3: col block (64 cols)
    const int row0 = blockIdx.x * BT;
    const int c    = blockIdx.y;
    int cnt = gcnt[c]; if (cnt > KP) cnt = KP;
    const int nch = (cnt + 31) >> 5;

    auto Hb = [&](int r, int k) -> char* {   // H bf16 [64][256] swizzled
        return sm + r * 512 + ((((k >> 3) ^ (r & 7)) << 4) | ((k & 7) << 1));
    };
    auto XLb = [&](int r, int k) -> char* {  // X bf16 [64][320] swizzled
        return sm + r * 640 + ((((k >> 3) ^ (r & 7)) << 4) | ((k & 7) << 1));
    };
    auto stage_w1 = [&](int ch, int base) {  // 16 KB chunk, 2 DMA/thread
        const unsigned short* g = w1s + ((size_t)(c * NCH + ch)) * 8192;
        gld16(g + t * 8,        sm + base + t * 16);
        gld16(g + 4096 + t * 8, sm + base + 8192 + t * 16);
    };
    auto aread = [&](int base, int col, int unit) -> short8 { // staged frag read
        return *(const short8*)(sm + base + col * 64 + ((unit ^ ((col >> 1) & 3)) << 4));
    };

    // issue first W1 chunk stage immediately (flies under the whole gather)
    stage_w1(0, WB0);

    // ---------------- phase 0: gather ALL of Xc into LDS --------------------
    {
        const int gl2 = t & 63;         // gene-in-group
        const int rg  = t >> 6;         // row-group (8 rows)
        short8 xv[5];
        int kk[5];
        #pragma unroll
        for (int i = 0; i < 5; ++i) {
            kk[i] = i * 64 + gl2;
            xv[i] = short8{0,0,0,0,0,0,0,0};
            if (kk[i] < cnt) {
                int g = gidx[c * GS + kk[i]];
                xv[i] = *(const short8*)(xt + (size_t)g * NB + row0 + rg * 8);
            }
        }
        #pragma unroll
        for (int i = 0; i < 5; ++i)
            #pragma unroll
            for (int j = 0; j < 8; ++j)
                *(short*)XLb(rg * 8 + j, kk[i]) = xv[i][j];
    }
    __syncthreads();   // drains gather ds_writes AND WB0 stage

    // ---------------- stage A: h1 = leaky(Xc @ W1c + b1), staged 2-buf ------
    f32x4 acc[2][4];
    #pragma unroll
    for (int nn = 0; nn < 2; ++nn)
        #pragma unroll
        for (int mm = 0; mm < 4; ++mm) acc[nn][mm] = f32x4{0.f, 0.f, 0.f, 0.f};

    for (int ch = 0; ch < nch; ++ch) {
        const int cur = (ch & 1) ? WB1 : WB0;
        const int nxt = (ch & 1) ? WB0 : WB1;
        if (ch + 1 < nch) stage_w1(ch + 1, nxt);
        short8 a[4], b[2];
        #pragma unroll
        for (int mm = 0; mm < 4; ++mm)
            a[mm] = aread(cur, wh * 64 + mm * 16 + lr, lg);
        #pragma unroll
        for (int nn = 0; nn < 2; ++nn)
            b[nn] = *(const short8*)XLb(wb * 32 + nn * 16 + lr, ch * 32 + lg * 8);
        #pragma unroll
        for (int nn = 0; nn < 2; ++nn)
            #pragma unroll
            for (int mm = 0; mm < 4; ++mm)
                acc[nn][mm] = __builtin_amdgcn_mfma_f32_16x16x32_bf16(a[mm], b[nn], acc[nn][mm], 0, 0, 0);
        __syncthreads();   // drains nxt stage; fences cur reuse
    }

    // epilogue A: bias + leaky -> H (overlays X region)
    #pragma unroll
    for (int mm = 0; mm < 4; ++mm) {
        int k0 = wh * 64 + mm * 16 + lg * 4;
        f32x4 b1v = *(const f32x4*)(b1 + k0);
        #pragma unroll
        for (int nn = 0; nn < 2; ++nn) {
            int r = wb * 32 + nn * 16 + lr;
            float v0 = acc[nn][mm][0] + b1v[0]; v0 = (v0 >= 0.f) ? v0 : 0.01f * v0;
            float v1 = acc[nn][mm][1] + b1v[1]; v1 = (v1 >= 0.f) ? v1 : 0.01f * v1;
            float v2 = acc[nn][mm][2] + b1v[2]; v2 = (v2 >= 0.f) ? v2 : 0.01f * v2;
            float v3 = acc[nn][mm][3] + b1v[3]; v3 = (v3 >= 0.f) ? v3 : 0.01f * v3;
            uint2v pk;
            pk[0] = cvt_pk_bf16(v0, v1);
            pk[1] = cvt_pk_bf16(v2, v3);
            *(uint2v*)Hb(r, k0) = pk;
        }
    }
    __syncthreads();

    // ---------------- stage B: h2 = leaky(h1 @ W2 + b2) ---------------------
    // Direct per-wave global a-frags (L2-resident w2s), ZERO barriers inside.
    f32x4 acc2[2][4];
    #pragma unroll
    for (int nn = 0; nn < 2; ++nn)
        #pragma unroll
        for (int mm = 0; mm < 4; ++mm) acc2[nn][mm] = f32x4{0.f, 0.f, 0.f, 0.f};
    #pragma unroll
    for (int ch2 = 0; ch2 < 8; ++ch2) {
        short8 a[4], b[2];
        #pragma unroll
        for (int mm = 0; mm < 4; ++mm) {
            int col = wh * 64 + mm * 16 + lr;
            a[mm] = *(const short8*)(w2s + ((size_t)ch2 * 256 + col) * 32 +
                                     ((lg ^ ((col >> 1) & 3)) << 3));
        }
        #pragma unroll
        for (int nn = 0; nn < 2; ++nn)
            b[nn] = *(const short8*)Hb(wb * 32 + nn * 16 + lr, ch2 * 32 + lg * 8);
        #pragma unroll
        for (int nn = 0; nn < 2; ++nn)
            #pragma unroll
            for (int mm = 0; mm < 4; ++mm)
                acc2[nn][mm] = __builtin_amdgcn_mfma_f32_16x16x32_bf16(a[mm], b[nn], acc2[nn][mm], 0, 0, 0);
    }
    __syncthreads();    // all H(h1) reads complete before overwrite

    // epilogue B: h2 -> H (overwrite) + stage protos/i2e/cbias
    {
        #pragma unroll
        for (int mm = 0; mm < 4; ++mm) {
            int k0 = wh * 64 + mm * 16 + lg * 4;
            f32x4 b2v = *(const f32x4*)(b2 + k0);
            #pragma unroll
            for (int nn = 0; nn < 2; ++nn) {
                int r = wb * 32 + nn * 16 + lr;
                float v0 = acc2[nn][mm][0] + b2v[0]; v0 = (v0 >= 0.f) ? v0 : 0.01f * v0;
                float v1 = acc2[nn][mm][1] + b2v[1]; v1 = (v1 >= 0.f) ? v1 : 0.01f * v1;
                float v2 = acc2[nn][mm][2] + b2v[2]; v2 = (v2 >= 0.f) ? v2 : 0.01f * v2;
                float v3 = acc2[nn][mm][3] + b2v[3]; v3 = (v3 >= 0.f) ? v3 : 0.01f * v3;
                uint2v pk;
                pk[0] = cvt_pk_bf16(v0, v1);
                pk[1] = cvt_pk_bf16(v2, v3);
                *(uint2v*)Hb(r, k0) = pk;
            }
        }
        float* pp = (float*)(sm + PP_OFF);
        for (int i = t; i < NK * NP * NZD; i += 512)
            pp[(i >> 5) * 36 + (i & 31)] = protos[(size_t)c * (NK * NP * NZD) + i];
        if (t < NK * NP) pp[1440 + t] = 0.5f * expf(-logvar[c * (NK * NP) + t]);
        if (t < NK)      pp[1480 + t] = c_bias[c * NK + t];
    }
    __syncthreads();

    // ---------------- stage C: Z = h2 @ cw^T + cb (direct cwb, no staging) --
    {
        const int rt = w & 3, ot = w >> 2;
        const int o = ot * 16 + lr;
        f32x4 az = f32x4{0.f, 0.f, 0.f, 0.f};
        #pragma unroll
        for (int ch = 0; ch < 8; ++ch) {
            short8 afr = *(const short8*)(cwb + (size_t)c * 8192 + o * 256 +
                                          ((((ch << 2) + lg) ^ (o & 7)) << 3));
            short8 bfr = *(const short8*)Hb(rt * 16 + lr, ch * 32 + lg * 8);
            az = __builtin_amdgcn_mfma_f32_16x16x32_bf16(afr, bfr, az, 0, 0, 0);
        }
        f32x4 cb4 = *(const f32x4*)(cb + c * NZD + ot * 16 + lg * 4);
        float* SZ = (float*)(sm + WB0);
        #pragma unroll
        for (int i = 0; i < 4; ++i)
            SZ[(rt * 16 + lr) * 36 + ot * 16 + lg * 4 + i] = az[i] + cb4[i];
    }
    __syncthreads();

    // ---------------- stage D: prototype distances -> c_logits --------------
    {
        const float* SZ  = (const float*)(sm + WB0);
        const float* pp  = (const float*)(sm + PP_OFF);
        const float* i2e = pp + 1440;
        const float* cbs = pp + 1480;
        const int rloc = (w & 3) * 16 + lr;
        f32x4 z[8];
        #pragma unroll
        for (int j = 0; j < 8; ++j)
            z[j] = *(const f32x4*)(SZ + rloc * 36 + j * 4);
        const int kk0 = (w >> 2) * 5;
        #pragma unroll
        for (int kk = kk0; kk < kk0 + 5; ++kk) {
            int kp = kk * NP + lg;       // lg == p
            f32x4 d = f32x4{0.f, 0.f, 0.f, 0.f};
            #pragma unroll
            for (int j = 0; j < 8; ++j) {
                f32x4 p = *(const f32x4*)(pp + kp * 36 + j * 4);
                f32x4 df = z[j] - p;
                d += df * df;
            }
            float sc = ((d[0] + d[1]) + (d[2] + d[3])) * i2e[kp];
            sc = fminf(sc, __shfl_xor(sc, 16));
            sc = fminf(sc, __shfl_xor(sc, 32));
            if (lg == 0)
                out_cl[((size_t)(row0 + rloc) * NC + c) * NK + kk] = cbs[kk] - sc;
        }
    }
}

// ---------------- fallback (round-1 fp32 path, known-good) -----------------
__global__ __launch_bounds__(256, 1) void fused_main(
    const float* __restrict__ X,  const float* __restrict__ W1,
    const float* __restrict__ b1, const float* __restrict__ W2,
    const float* __restrict__ b2, const float* __restrict__ cw,
    const float* __restrict__ cb, const float* __restrict__ protos,
    const float* __restrict__ logvar, const float* __restrict__ c_bias,
    const int* __restrict__ gidx, const int* __restrict__ gcnt,
    float* __restrict__ out_cl)
{
    extern __shared__ float smemf[];
    float (*sh_big)[258] = (float (*)[258])smemf;
    float (*sh_w)[258]   = (float (*)[258])(smemf + 16512);
    float (*sh_x)[33]    = (float (*)[33])(smemf + 16512 + 8256);
    int*  sh_gid         = (int*)(smemf + 16512 + 8256 + 2112);

    const int t   = threadIdx.x;
    const int tx  = t & 15;
    const int ty  = t >> 4;
    const int row0 = blockIdx.x * 64;
    const int c    = blockIdx.y;

    float acc[4][16];
    #pragma unroll
    for (int i = 0; i < 4; ++i)
        #pragma unroll
        for (int l = 0; l < 16; ++l) acc[i][l] = 0.f;

    const int cnt = gcnt[c];
    const int nch = (cnt + 31) >> 5;
    for (int ch = 0; ch < nch; ++ch) {
        __syncthreads();
        if (t < 32) {
            int gi = ch * 32 + t;
            sh_gid[t] = (gi < cnt) ? gidx[c * GS + gi] : -1;
        }
        __syncthreads();
        #pragma unroll 4
        for (int jj = 0; jj < 32; ++jj) {
            int g = sh_gid[jj];
            sh_w[jj][t] = (g >= 0) ? W1[g * NH + t] : 0.f;
        }
        {
            int j  = t & 31;
            int rb2 = (t >> 5) * 8;
            int g  = sh_gid[j];
            #pragma unroll
            for (int ii = 0; ii < 8; ++ii)
                sh_x[rb2 + ii][j] = (g >= 0) ? X[(size_t)(row0 + rb2 + ii) * NG + g] : 0.f;
        }
        __syncthreads();
        #pragma unroll 8
        for (int j = 0; j < 32; ++j) {
            float xv[4];
            #pragma unroll
            for (int i = 0; i < 4; ++i) xv[i] = sh_x[ty * 4 + i][j];
            #pragma unroll
            for (int l = 0; l < 16; ++l) {
                float wv = sh_w[j][l * 16 + tx];
                #pragma unroll
                for (int i = 0; i < 4; ++i) acc[i][l] = fmaf(xv[i], wv, acc[i][l]);
            }
        }
    }
    #pragma unroll
    for (int i = 0; i < 4; ++i)
        #pragma unroll
        for (int l = 0; l < 16; ++l) {
            int col = l * 16 + tx;
            float v = acc[i][l] + b1[col];
            sh_big[ty * 4 + i][col] = (v >= 0.f) ? v : 0.01f * v;
        }

    float acc2[4][16];
    #pragma unroll
    for (int i = 0; i < 4; ++i)
        #pragma unroll
        for (int l = 0; l < 16; ++l) acc2[i][l] = 0.f;
    for (int ch = 0; ch < NH / 32; ++ch) {
        __syncthreads();
        #pragma unroll 4
        for (int jj = 0; jj < 32; ++jj)
            sh_w[jj][t] = W2[(size_t)(ch * 32 + jj) * NH + t];
        __syncthreads();
        #pragma unroll 8
        for (int j = 0; j < 32; ++j) {
            float xv[4];
            #pragma unroll
            for (int i = 0; i < 4; ++i) xv[i] = sh_big[ty * 4 + i][ch * 32 + j];
            #pragma unroll
            for (int l = 0; l < 16; ++l) {
                float wv = sh_w[j][l * 16 + tx];
                #pragma unroll
                for (int i = 0; i < 4; ++i) acc2[i][l] = fmaf(xv[i], wv, acc2[i][l]);
            }
        }
    }
    __syncthreads();
    #pragma unroll
    for (int i = 0; i < 4; ++i)
        #pragma unroll
        for (int l = 0; l < 16; ++l) {
            int col = l * 16 + tx;
            float v = acc2[i][l] + b2[col];
            sh_big[ty * 4 + i][col] = (v >= 0.f) ? v : 0.01f * v;
        }
    #pragma unroll 4
    for (int o = 0; o < NZD; ++o)
        sh_w[o][t] = cw[((size_t)c * NZD + o) * NH + t];
    __syncthreads();
    {
        int o  = t & 31;
        int rg = t >> 5;
        float cbv = cb[c * NZD + o];
        float zv[8];
        #pragma unroll
        for (int i = 0; i < 8; ++i) zv[i] = cbv;
        for (int h = 0; h < NH; ++h) {
            float wv = sh_w[o][h];
            #pragma unroll
            for (int i = 0; i < 8; ++i)
                zv[i] = fmaf(sh_big[rg * 8 + i][h], wv, zv[i]);
        }
        #pragma unroll
        for (int i = 0; i < 8; ++i) sh_x[rg * 8 + i][o] = zv[i];
    }
    __syncthreads();
    float* proto_s = &sh_w[0][0];
    float* i2e_s   = proto_s + NK * NP * NZD;
    float* cbias_s = i2e_s + NK * NP;
    for (int i = t; i < NK * NP * NZD; i += 256)
        proto_s[i] = protos[(size_t)c * NK * NP * NZD + i];
    if (t < NK * NP) i2e_s[t] = 0.5f * expf(-logvar[c * NK * NP + t]);
    if (t < NK)      cbias_s[t] = c_bias[c * NK + t];
    __syncthreads();
    for (int task = t; task < 64 * NK; task += 256) {
        int r = task / NK;
        int k = task - r * NK;
        float best = 3.4e38f;
        #pragma unroll
        for (int p = 0; p < NP; ++p) {
            float d2 = 0.f;
            const float* ppr = proto_s + (k * NP + p) * NZD;
            #pragma unroll
            for (int o = 0; o < NZD; ++o) {
                float dv = sh_x[r][o] - ppr[o];
                d2 = fmaf(dv, dv, d2);
            }
            float sc = d2 * i2e_s[k * NP + p];
            best = fminf(best, sc);
        }
        out_cl[((size_t)(row0 + r) * NC + c) * NK + k] = cbias_s[k] - best;
    }
}

// ---------------- logits reduce ---------------------------------------------
__global__ void reduce_logits(const float* __restrict__ cl,
                              const float* __restrict__ importance,
                              const float* __restrict__ bias,
                              float* __restrict__ out) {
    int idx = blockIdx.x * blockDim.x + threadIdx.x;
    if (idx >= NB * NK) return;
    int b = idx / NK;
    int k = idx - b * NK;
    float s = 0.f;
    #pragma unroll
    for (int c = 0; c < NC; ++c) {
        float imp = fabsf(importance[c]);
        s += expf(cl[((size_t)b * NC + c) * NK + k]) * imp + 1e-16f;
    }
    out[idx] = logf(s) + bias[k];
}

extern "C" void kernel_launch(void* const* d_in, const int* in_sizes, int n_in,
                              void* d_out, int out_size, void* d_ws, size_t ws_size,
                              hipStream_t stream) {
    const float* X      = (const float*)d_in[0];
    const float* M      = (const float*)d_in[1];
    const float* W1     = (const float*)d_in[2];
    const float* b1     = (const float*)d_in[3];
    const float* W2     = (const float*)d_in[4];
    const float* b2     = (const float*)d_in[5];
    const float* cw     = (const float*)d_in[6];
    const float* cb     = (const float*)d_in[7];
    const float* protos = (const float*)d_in[8];
    const float* logvar = (const float*)d_in[9];
    const float* c_bias = (const float*)d_in[10];
    const float* bias   = (const float*)d_in[11];
    const float* imp    = (const float*)d_in[12];

    float* out_logits = (float*)d_out;
    float* out_cl     = out_logits + NB * NK;

    // workspace layout (bytes)
    const size_t o_gcnt = (size_t)NC * GS * 4;
    const size_t o_w1s  = o_gcnt + 256;
    const size_t o_w2s  = o_w1s + (size_t)NC * NCH * 256 * 32 * 2;
    const size_t o_cwb  = o_w2s + (size_t)8 * 256 * 32 * 2;
    const size_t o_xt   = o_cwb + (size_t)NC * 32 * 256 * 2;
    const size_t need   = o_xt + (size_t)NG * NB * 2;

    int* gidx = (int*)d_ws;
    int* gcnt = (int*)((char*)d_ws + o_gcnt);
    unsigned short* w1s = (unsigned short*)((char*)d_ws + o_w1s);
    unsigned short* w2s = (unsigned short*)((char*)d_ws + o_w2s);
    unsigned short* cwb = (unsigned short*)((char*)d_ws + o_cwb);
    unsigned short* xt  = (unsigned short*)((char*)d_ws + o_xt);

    build_gidx<<<NC, 1024, 0, stream>>>(M, gidx, gcnt);

    if (ws_size >= need) {
        prep_all<<<1582, 256, 0, stream>>>(X, W1, W2, cw, gidx, gcnt, xt, w1s, w2s, cwb);
        fused_mfma10<<<dim3(NB / BT, NC), 512, LDS_BYTES, stream>>>(
            xt, w1s, w2s, cwb, b1, b2, cb, protos, logvar, c_bias, gidx, gcnt, out_cl);
    } else {
        size_t smem = (size_t)(16512 + 8256 + 2112) * 4 + 32 * 4;
        fused_main<<<dim3(NB / 64, NC), 256, smem, stream>>>(
            X, W1, b1, W2, b2, cw, cb, protos, logvar, c_bias, gidx, gcnt, out_cl);
    }
    reduce_logits<<<(NB * NK + 255) / 256, 256, 0, stream>>>(out_cl, imp, bias, out_logits);
}

// Round 13
// 86.792 us; speedup vs baseline: 1.1925x; 1.0058x over previous
//
#include <hip/hip_runtime.h>
#include <hip/hip_bf16.h>

#define NB   2048
#define NG   2000
#define NC   50
#define NH   256
#define NZD  32
#define NK   10
#define NP   4
#define BT   64
#define GS   2048
#define KP   320
#define NCH  10      // KP/32

typedef short short8  __attribute__((ext_vector_type(8)));
typedef short short4v __attribute__((ext_vector_type(4)));
typedef float f32x4   __attribute__((ext_vector_type(4)));
typedef unsigned int uint2v __attribute__((ext_vector_type(2)));

__device__ __forceinline__ unsigned short f2bf(float f) {
    union { float f; unsigned u; } v; v.f = f;
    unsigned r = v.u + 0x7fffu + ((v.u >> 16) & 1u);
    return (unsigned short)(r >> 16);
}

__device__ __forceinline__ unsigned cvt_pk_bf16(float lo, float hi) {
    unsigned r;
    asm("v_cvt_pk_bf16_f32 %0, %1, %2" : "=v"(r) : "v"(lo), "v"(hi));
    return r;
}

// async 16B global->LDS (no VGPR round-trip, counted by vmcnt)
__device__ __forceinline__ void gld16(const unsigned short* g, char* l) {
    __builtin_amdgcn_global_load_lds(
        (const __attribute__((address_space(1))) unsigned int*)g,
        (__attribute__((address_space(3))) unsigned int*)l, 16, 0, 0);
}

// ---------------- deterministic ordered compaction of M (1024 thr) ---------
__global__ void build_gidx(const float* __restrict__ M, int* __restrict__ gidx,
                           int* __restrict__ gcnt) {
    int c = blockIdx.x;
    int t = threadIdx.x;
    __shared__ int wcnt[16];
    __shared__ int base;
    if (t == 0) base = 0;
    __syncthreads();
    for (int g0 = 0; g0 < NG; g0 += 1024) {
        int g = g0 + t;
        bool a = (g < NG) && (M[c * NG + g] != 0.0f);
        unsigned long long mask = __ballot(a);
        int lane = t & 63;
        int w = t >> 6;
        if (lane == 0) wcnt[w] = __popcll(mask);
        int pre = __popcll(mask & ((1ull << lane) - 1ull));
        __syncthreads();
        int woff = base;
        for (int i = 0; i < w; ++i) woff += wcnt[i];
        if (a) gidx[c * GS + woff + pre] = g;
        int tot = 0;
        #pragma unroll
        for (int i = 0; i < 16; ++i) tot += wcnt[i];
        __syncthreads();
        if (t == 0) base += tot;
        __syncthreads();
    }
    if (t == 0) gcnt[c] = base;
}

// ---------------- merged prep kernel ---------------------------------------
// blocks [0,1024): X transpose; [1024,1524): w1s; [1524,1532): w2s; [1532,1582): cwb
// w1s/w2s: fragment-order [col][32k], 16B unit q stored at q ^ ((col>>1)&3)
// cwb: [o][256h], 16B unit u stored at u ^ (o&7)
__global__ void prep_all(const float* __restrict__ X, const float* __restrict__ W1,
                         const float* __restrict__ W2, const float* __restrict__ cw,
                         const int* __restrict__ gidx, const int* __restrict__ gcnt,
                         unsigned short* __restrict__ xt, unsigned short* __restrict__ w1s,
                         unsigned short* __restrict__ w2s, unsigned short* __restrict__ cwb) {
    __shared__ float tile[64][65];
    const int bx = blockIdx.x;
    const int t  = threadIdx.x;
    if (bx < 1024) {                       // ---- xt: X^T to bf16, gene-major
        int gb = bx & 31, bb = bx >> 5;
        int tx = t & 63, tq = t >> 6;
        #pragma unroll
        for (int i = 0; i < 16; ++i) {
            int r = tq * 16 + i;
            int gene = gb * 64 + tx;
            tile[r][tx] = (gene < NG) ? X[(size_t)(bb * 64 + r) * NG + gene] : 0.f;
        }
        __syncthreads();
        #pragma unroll
        for (int i = 0; i < 16; ++i) {
            int gl = tq * 16 + i;
            int gene = gb * 64 + gl;
            if (gene < NG)
                xt[(size_t)gene * NB + bb * 64 + tx] = f2bf(tile[tx][gl]);
        }
    } else if (bx < 1524) {                // ---- w1s: gathered W1
        int idx = bx - 1024;
        int ch = idx % NCH, c = idx / NCH;
        int col = t;
        int cnt = gcnt[c]; if (cnt > KP) cnt = KP;
        unsigned short v[32];
        #pragma unroll
        for (int kin = 0; kin < 32; ++kin) {
            int k = ch * 32 + kin;
            float x = 0.f;
            if (k < cnt) {
                int g = gidx[c * GS + k];
                x = W1[(size_t)g * NH + col];
            }
            v[kin] = f2bf(x);
        }
        unsigned short* dst = w1s + (((size_t)(c * NCH + ch)) * 256 + col) * 32;
        #pragma unroll
        for (int q = 0; q < 4; ++q) {
            short8 v8;
            #pragma unroll
            for (int i = 0; i < 8; ++i) v8[i] = (short)v[q * 8 + i];
            *(short8*)(dst + (q ^ ((col >> 1) & 3)) * 8) = v8;
        }
    } else if (bx < 1532) {                // ---- w2s: W2^T chunks
        int ch = bx - 1524;
        int col = t;
        unsigned short v[32];
        #pragma unroll
        for (int kin = 0; kin < 32; ++kin)
            v[kin] = f2bf(W2[(size_t)(ch * 32 + kin) * NH + col]);
        unsigned short* dst = w2s + ((size_t)ch * 256 + col) * 32;
        #pragma unroll
        for (int q = 0; q < 4; ++q) {
            short8 v8;
            #pragma unroll
            for (int i = 0; i < 8; ++i) v8[i] = (short)v[q * 8 + i];
            *(short8*)(dst + (q ^ ((col >> 1) & 3)) * 8) = v8;
        }
    } else {                               // ---- cwb: cw -> bf16 [o][256], swizzled
        int c = bx - 1532;
        int o = t >> 3, seg = t & 7;
        #pragma unroll
        for (int blk = 0; blk < 4; ++blk) {
            int u = seg * 4 + blk;         // 16B unit (8 h's)
            short8 v8;
            #pragma unroll
            for (int i = 0; i < 8; ++i)
                v8[i] = (short)f2bf(cw[((size_t)c * NZD + o) * NH + u * 8 + i]);
            *(short8*)(cwb + (size_t)c * 8192 + o * 256 + (u ^ (o & 7)) * 8) = v8;
        }
    }
}

// ---------------- main fused kernel -----------------------------------------
// LDS (73728 B, 2 blocks/CU):
//   [0, 40960)      : X bf16 [64][320] swizzled (stage A); post-A:
//                     [0,32768) H bf16 [64][256] swizzled, [32768,40960) protos
//   [40960, 57344)  : W staging buf0 (16 KB) — later SCW or SZ
//   [57344, 73728)  : W staging buf1 (16 KB)
#define PP_OFF   32768
#define WB0      40960
#define WB1      57344
#define LDS_BYTES 73728

__global__ __launch_bounds__(512, 4) void fused_mfma12(
    const unsigned short* __restrict__ xt,
    const unsigned short* __restrict__ w1s,
    const unsigned short* __restrict__ w2s,
    const unsigned short* __restrict__ cwb,
    const float* __restrict__ b1, const float* __restrict__ b2,
    const float* __restrict__ cb, const float* __restrict__ protos,
    const float* __restrict__ logvar, const float* __restrict__ c_bias,
    const int* __restrict__ gidx, const int* __restrict__ gcnt,
    float* __restrict__ out_cl)
{
    extern __shared__ char sm[];
    const int t  = threadIdx.x;
    const int l  = t & 63;
    const int w  = t >> 6;      // 0..7
    const int lr = l & 15;
    const int lg = l >> 4;      // 0..3
    const int wb = w >> 2;      // 0..1: row block (32 rows)
    const int wh = w & 3;       // 0..3: col block (64 cols)
    const int row0 = blockIdx.x * BT;
    const int c    = blockIdx.y;
    int cnt = gcnt[c]; if (cnt > KP) cnt = KP;
    const int nch = (cnt + 31) >> 5;

    auto Hb = [&](int r, int k) -> char* {   // H bf16 [64][256] swizzled
        return sm + r * 512 + ((((k >> 3) ^ (r & 7)) << 4) | ((k & 7) << 1));
    };
    auto XLb = [&](int r, int k) -> char* {  // X bf16 [64][320] swizzled
        return sm + r * 640 + ((((k >> 3) ^ (r & 7)) << 4) | ((k & 7) << 1));
    };
    auto stage_w = [&](const unsigned short* gsrc, int base) {  // 16 KB chunk
        gld16(gsrc + t * 8,        sm + base + t * 16);
        gld16(gsrc + 4096 + t * 8, sm + base + 8192 + t * 16);
    };
    // a-fragment read from a staged W buffer (global pre-swizzle + read swizzle)
    auto aread = [&](int base, int col, int unit) -> short8 {
        return *(const short8*)(sm + base + col * 64 + ((unit ^ ((col >> 1) & 3)) << 4));
    };

    // issue first W1 chunk stage immediately (flies under the whole gather)
    stage_w(w1s + (size_t)c * NCH * 8192, WB0);

    // ---------------- phase 0: gather ALL of Xc into LDS --------------------
    {
        const int gl2 = t & 63;         // gene-in-group
        const int rg  = t >> 6;         // row-group (8 rows)
        short8 xv[5];
        int kk[5];
        #pragma unroll
        for (int i = 0; i < 5; ++i) {
            kk[i] = i * 64 + gl2;
            xv[i] = short8{0,0,0,0,0,0,0,0};
            if (kk[i] < cnt) {
                int g = gidx[c * GS + kk[i]];
                xv[i] = *(const short8*)(xt + (size_t)g * NB + row0 + rg * 8);
            }
        }
        #pragma unroll
        for (int i = 0; i < 5; ++i)
            #pragma unroll
            for (int j = 0; j < 8; ++j)
                *(short*)XLb(rg * 8 + j, kk[i]) = xv[i][j];
    }
    __syncthreads();   // drains gather ds_writes AND WB0 stage

    // ---------------- stage A: h1 = leaky(Xc @ W1c + b1), 2-phase pipe ------
    f32x4 acc[2][4];
    #pragma unroll
    for (int nn = 0; nn < 2; ++nn)
        #pragma unroll
        for (int mm = 0; mm < 4; ++mm) acc[nn][mm] = f32x4{0.f, 0.f, 0.f, 0.f};

    for (int ch = 0; ch < nch; ++ch) {
        const int cur = (ch & 1) ? WB1 : WB0;
        const int nxt = (ch & 1) ? WB0 : WB1;
        if (ch + 1 < nch) stage_w(w1s + (size_t)(c * NCH + ch + 1) * 8192, nxt);
        else              stage_w(w2s, nxt);             // chain into stage B
        short8 a[4], b[2];
        #pragma unroll
        for (int mm = 0; mm < 4; ++mm)
            a[mm] = aread(cur, wh * 64 + mm * 16 + lr, lg);
        #pragma unroll
        for (int nn = 0; nn < 2; ++nn)
            b[nn] = *(const short8*)XLb(wb * 32 + nn * 16 + lr, ch * 32 + lg * 8);
        #pragma unroll
        for (int nn = 0; nn < 2; ++nn)
            #pragma unroll
            for (int mm = 0; mm < 4; ++mm)
                acc[nn][mm] = __builtin_amdgcn_mfma_f32_16x16x32_bf16(a[mm], b[nn], acc[nn][mm], 0, 0, 0);
        __syncthreads();   // drains nxt stage; fences cur reuse
    }

    // epilogue A: bias + leaky -> H (overlays X region)
    #pragma unroll
    for (int mm = 0; mm < 4; ++mm) {
        int k0 = wh * 64 + mm * 16 + lg * 4;
        f32x4 b1v = *(const f32x4*)(b1 + k0);
        #pragma unroll
        for (int nn = 0; nn < 2; ++nn) {
            int r = wb * 32 + nn * 16 + lr;
            float v0 = acc[nn][mm][0] + b1v[0]; v0 = (v0 >= 0.f) ? v0 : 0.01f * v0;
            float v1 = acc[nn][mm][1] + b1v[1]; v1 = (v1 >= 0.f) ? v1 : 0.01f * v1;
            float v2 = acc[nn][mm][2] + b1v[2]; v2 = (v2 >= 0.f) ? v2 : 0.01f * v2;
            float v3 = acc[nn][mm][3] + b1v[3]; v3 = (v3 >= 0.f) ? v3 : 0.01f * v3;
            uint2v pk;
            pk[0] = cvt_pk_bf16(v0, v1);
            pk[1] = cvt_pk_bf16(v2, v3);
            *(uint2v*)Hb(r, k0) = pk;
        }
    }
    __syncthreads();

    // ---------------- stage B: h2 = leaky(h1 @ W2 + b2), 2-phase pipe -------
    f32x4 acc2[2][4];
    #pragma unroll
    for (int nn = 0; nn < 2; ++nn)
        #pragma unroll
        for (int mm = 0; mm < 4; ++mm) acc2[nn][mm] = f32x4{0.f, 0.f, 0.f, 0.f};
    for (int ch2 = 0; ch2 < 8; ++ch2) {
        const int cur = ((nch + ch2) & 1) ? WB1 : WB0;
        const int nxt = ((nch + ch2) & 1) ? WB0 : WB1;
        if (ch2 + 1 < 8) stage_w(w2s + (size_t)(ch2 + 1) * 8192, nxt);
        else             stage_w(cwb + (size_t)c * 8192, nxt);   // cw for stage C
        short8 a[4], b[2];
        #pragma unroll
        for (int mm = 0; mm < 4; ++mm)
            a[mm] = aread(cur, wh * 64 + mm * 16 + lr, lg);
        #pragma unroll
        for (int nn = 0; nn < 2; ++nn)
            b[nn] = *(const short8*)Hb(wb * 32 + nn * 16 + lr, ch2 * 32 + lg * 8);
        #pragma unroll
        for (int nn = 0; nn < 2; ++nn)
            #pragma unroll
            for (int mm = 0; mm < 4; ++mm)
                acc2[nn][mm] = __builtin_amdgcn_mfma_f32_16x16x32_bf16(a[mm], b[nn], acc2[nn][mm], 0, 0, 0);
        __syncthreads();
    }
    const int cwbase = ((nch + 8) & 1) ? WB1 : WB0;
    const int szbase = ((nch + 8) & 1) ? WB0 : WB1;

    // epilogue B: h2 -> H (overwrite) + stage protos/i2e/cbias
    {
        #pragma unroll
        for (int mm = 0; mm < 4; ++mm) {
            int k0 = wh * 64 + mm * 16 + lg * 4;
            f32x4 b2v = *(const f32x4*)(b2 + k0);
            #pragma unroll
            for (int nn = 0; nn < 2; ++nn) {
                int r = wb * 32 + nn * 16 + lr;
                float v0 = acc2[nn][mm][0] + b2v[0]; v0 = (v0 >= 0.f) ? v0 : 0.01f * v0;
                float v1 = acc2[nn][mm][1] + b2v[1]; v1 = (v1 >= 0.f) ? v1 : 0.01f * v1;
                float v2 = acc2[nn][mm][2] + b2v[2]; v2 = (v2 >= 0.f) ? v2 : 0.01f * v2;
                float v3 = acc2[nn][mm][3] + b2v[3]; v3 = (v3 >= 0.f) ? v3 : 0.01f * v3;
                uint2v pk;
                pk[0] = cvt_pk_bf16(v0, v1);
                pk[1] = cvt_pk_bf16(v2, v3);
                *(uint2v*)Hb(r, k0) = pk;
            }
        }
        float* pp = (float*)(sm + PP_OFF);
        for (int i = t; i < NK * NP * NZD; i += 512)
            pp[(i >> 5) * 36 + (i & 31)] = protos[(size_t)c * (NK * NP * NZD) + i];
        if (t < NK * NP) pp[1440 + t] = 0.5f * expf(-logvar[c * (NK * NP) + t]);
        if (t < NK)      pp[1480 + t] = c_bias[c * NK + t];
    }
    __syncthreads();   // also drains the cw stage

    // ---------------- stage C: Z = h2 @ cw^T + cb (all 8 waves, LDS-fed) ----
    {
        const int rt = w & 3, ot = w >> 2;
        const int o = ot * 16 + lr;
        f32x4 az = f32x4{0.f, 0.f, 0.f, 0.f};
        #pragma unroll
        for (int ch = 0; ch < 8; ++ch) {
            short8 afr = *(const short8*)(sm + cwbase + o * 512 +
                                          ((((ch << 2) + lg) ^ (o & 7)) << 4));
            short8 bfr = *(const short8*)Hb(rt * 16 + lr, ch * 32 + lg * 8);
            az = __builtin_amdgcn_mfma_f32_16x16x32_bf16(afr, bfr, az, 0, 0, 0);
        }
        f32x4 cb4 = *(const f32x4*)(cb + c * NZD + ot * 16 + lg * 4);
        float* SZ = (float*)(sm + szbase);
        #pragma unroll
        for (int i = 0; i < 4; ++i)
            SZ[(rt * 16 + lr) * 36 + ot * 16 + lg * 4 + i] = az[i] + cb4[i];
    }
    __syncthreads();

    // ---------------- stage D: prototype distances -> c_logits --------------
    {
        const float* SZ  = (const float*)(sm + szbase);
        const float* pp  = (const float*)(sm + PP_OFF);
        const float* i2e = pp + 1440;
        const float* cbs = pp + 1480;
        const int rloc = (w & 3) * 16 + lr;
        f32x4 z[8];
        #pragma unroll
        for (int j = 0; j < 8; ++j)
            z[j] = *(const f32x4*)(SZ + rloc * 36 + j * 4);
        const int kk0 = (w >> 2) * 5;
        #pragma unroll
        for (int kk = kk0; kk < kk0 + 5; ++kk) {
            int kp = kk * NP + lg;       // lg == p
            f32x4 d = f32x4{0.f, 0.f, 0.f, 0.f};
            #pragma unroll
            for (int j = 0; j < 8; ++j) {
                f32x4 p = *(const f32x4*)(pp + kp * 36 + j * 4);
                f32x4 df = z[j] - p;
                d += df * df;
            }
            float sc = ((d[0] + d[1]) + (d[2] + d[3])) * i2e[kp];
            sc = fminf(sc, __shfl_xor(sc, 16));
            sc = fminf(sc, __shfl_xor(sc, 32));
            if (lg == 0)
                out_cl[((size_t)(row0 + rloc) * NC + c) * NK + kk] = cbs[kk] - sc;
        }
    }
}

// ---------------- fallback (round-1 fp32 path, known-good) -----------------
__global__ __launch_bounds__(256, 1) void fused_main(
    const float* __restrict__ X,  const float* __restrict__ W1,
    const float* __restrict__ b1, const float* __restrict__ W2,
    const float* __restrict__ b2, const float* __restrict__ cw,
    const float* __restrict__ cb, const float* __restrict__ protos,
    const float* __restrict__ logvar, const float* __restrict__ c_bias,
    const int* __restrict__ gidx, const int* __restrict__ gcnt,
    float* __restrict__ out_cl)
{
    extern __shared__ float smemf[];
    float (*sh_big)[258] = (float (*)[258])smemf;
    float (*sh_w)[258]   = (float (*)[258])(smemf + 16512);
    float (*sh_x)[33]    = (float (*)[33])(smemf + 16512 + 8256);
    int*  sh_gid         = (int*)(smemf + 16512 + 8256 + 2112);

    const int t   = threadIdx.x;
    const int tx  = t & 15;
    const int ty  = t >> 4;
    const int row0 = blockIdx.x * 64;
    const int c    = blockIdx.y;

    float acc[4][16];
    #pragma unroll
    for (int i = 0; i < 4; ++i)
        #pragma unroll
        for (int l = 0; l < 16; ++l) acc[i][l] = 0.f;

    const int cnt = gcnt[c];
    const int nch = (cnt + 31) >> 5;
    for (int ch = 0; ch < nch; ++ch) {
        __syncthreads();
        if (t < 32) {
            int gi = ch * 32 + t;
            sh_gid[t] = (gi < cnt) ? gidx[c * GS + gi] : -1;
        }
        __syncthreads();
        #pragma unroll 4
        for (int jj = 0; jj < 32; ++jj) {
            int g = sh_gid[jj];
            sh_w[jj][t] = (g >= 0) ? W1[g * NH + t] : 0.f;
        }
        {
            int j  = t & 31;
            int rb2 = (t >> 5) * 8;
            int g  = sh_gid[j];
            #pragma unroll
            for (int ii = 0; ii < 8; ++ii)
                sh_x[rb2 + ii][j] = (g >= 0) ? X[(size_t)(row0 + rb2 + ii) * NG + g] : 0.f;
        }
        __syncthreads();
        #pragma unroll 8
        for (int j = 0; j < 32; ++j) {
            float xv[4];
            #pragma unroll
            for (int i = 0; i < 4; ++i) xv[i] = sh_x[ty * 4 + i][j];
            #pragma unroll
            for (int l = 0; l < 16; ++l) {
                float wv = sh_w[j][l * 16 + tx];
                #pragma unroll
                for (int i = 0; i < 4; ++i) acc[i][l] = fmaf(xv[i], wv, acc[i][l]);
            }
        }
    }
    #pragma unroll
    for (int i = 0; i < 4; ++i)
        #pragma unroll
        for (int l = 0; l < 16; ++l) {
            int col = l * 16 + tx;
            float v = acc[i][l] + b1[col];
            sh_big[ty * 4 + i][col] = (v >= 0.f) ? v : 0.01f * v;
        }

    float acc2[4][16];
    #pragma unroll
    for (int i = 0; i < 4; ++i)
        #pragma unroll
        for (int l = 0; l < 16; ++l) acc2[i][l] = 0.f;
    for (int ch = 0; ch < NH / 32; ++ch) {
        __syncthreads();
        #pragma unroll 4
        for (int jj = 0; jj < 32; ++jj)
            sh_w[jj][t] = W2[(size_t)(ch * 32 + jj) * NH + t];
        __syncthreads();
        #pragma unroll 8
        for (int j = 0; j < 32; ++j) {
            float xv[4];
            #pragma unroll
            for (int i = 0; i < 4; ++i) xv[i] = sh_big[ty * 4 + i][ch * 32 + j];
            #pragma unroll
            for (int l = 0; l < 16; ++l) {
                float wv = sh_w[j][l * 16 + tx];
                #pragma unroll
                for (int i = 0; i < 4; ++i) acc2[i][l] = fmaf(xv[i], wv, acc2[i][l]);
            }
        }
    }
    __syncthreads();
    #pragma unroll
    for (int i = 0; i < 4; ++i)
        #pragma unroll
        for (int l = 0; l < 16; ++l) {
            int col = l * 16 + tx;
            float v = acc2[i][l] + b2[col];
            sh_big[ty * 4 + i][col] = (v >= 0.f) ? v : 0.01f * v;
        }
    #pragma unroll 4
    for (int o = 0; o < NZD; ++o)
        sh_w[o][t] = cw[((size_t)c * NZD + o) * NH + t];
    __syncthreads();
    {
        int o  = t & 31;
        int rg = t >> 5;
        float cbv = cb[c * NZD + o];
        float zv[8];
        #pragma unroll
        for (int i = 0; i < 8; ++i) zv[i] = cbv;
        for (int h = 0; h < NH; ++h) {
            float wv = sh_w[o][h];
            #pragma unroll
            for (int i = 0; i < 8; ++i)
                zv[i] = fmaf(sh_big[rg * 8 + i][h], wv, zv[i]);
        }
        #pragma unroll
        for (int i = 0; i < 8; ++i) sh_x[rg * 8 + i][o] = zv[i];
    }
    __syncthreads();
    float* proto_s = &sh_w[0][0];
    float* i2e_s   = proto_s + NK * NP * NZD;
    float* cbias_s = i2e_s + NK * NP;
    for (int i = t; i < NK * NP * NZD; i += 256)
        proto_s[i] = protos[(size_t)c * NK * NP * NZD + i];
    if (t < NK * NP) i2e_s[t] = 0.5f * expf(-logvar[c * NK * NP + t]);
    if (t < NK)      cbias_s[t] = c_bias[c * NK + t];
    __syncthreads();
    for (int task = t; task < 64 * NK; task += 256) {
        int r = task / NK;
        int k = task - r * NK;
        float best = 3.4e38f;
        #pragma unroll
        for (int p = 0; p < NP; ++p) {
            float d2 = 0.f;
            const float* ppr = proto_s + (k * NP + p) * NZD;
            #pragma unroll
            for (int o = 0; o < NZD; ++o) {
                float dv = sh_x[r][o] - ppr[o];
                d2 = fmaf(dv, dv, d2);
            }
            float sc = d2 * i2e_s[k * NP + p];
            best = fminf(best, sc);
        }
        out_cl[((size_t)(row0 + r) * NC + c) * NK + k] = cbias_s[k] - best;
    }
}

// ---------------- logits reduce ---------------------------------------------
__global__ void reduce_logits(const float* __restrict__ cl,
                              const float* __restrict__ importance,
                              const float* __restrict__ bias,
                              float* __restrict__ out) {
    int idx = blockIdx.x * blockDim.x + threadIdx.x;
    if (idx >= NB * NK) return;
    int b = idx / NK;
    int k = idx - b * NK;
    float s = 0.f;
    #pragma unroll
    for (int c = 0; c < NC; ++c) {
        float imp = fabsf(importance[c]);
        s += expf(cl[((size_t)b * NC + c) * NK + k]) * imp + 1e-16f;
    }
    out[idx] = logf(s) + bias[k];
}

extern "C" void kernel_launch(void* const* d_in, const int* in_sizes, int n_in,
                              void* d_out, int out_size, void* d_ws, size_t ws_size,
                              hipStream_t stream) {
    const float* X      = (const float*)d_in[0];
    const float* M      = (const float*)d_in[1];
    const float* W1     = (const float*)d_in[2];
    const float* b1     = (const float*)d_in[3];
    const float* W2     = (const float*)d_in[4];
    const float* b2     = (const float*)d_in[5];
    const float* cw     = (const float*)d_in[6];
    const float* cb     = (const float*)d_in[7];
    const float* protos = (const float*)d_in[8];
    const float* logvar = (const float*)d_in[9];
    const float* c_bias = (const float*)d_in[10];
    const float* bias   = (const float*)d_in[11];
    const float* imp    = (const float*)d_in[12];

    float* out_logits = (float*)d_out;
    float* out_cl     = out_logits + NB * NK;

    // workspace layout (bytes)
    const size_t o_gcnt = (size_t)NC * GS * 4;
    const size_t o_w1s  = o_gcnt + 256;
    const size_t o_w2s  = o_w1s + (size_t)NC * NCH * 256 * 32 * 2;
    const size_t o_cwb  = o_w2s + (size_t)8 * 256 * 32 * 2;
    const size_t o_xt   = o_cwb + (size_t)NC * 32 * 256 * 2;
    const size_t need   = o_xt + (size_t)NG * NB * 2;

    int* gidx = (int*)d_ws;
    int* gcnt = (int*)((char*)d_ws + o_gcnt);
    unsigned short* w1s = (unsigned short*)((char*)d_ws + o_w1s);
    unsigned short* w2s = (unsigned short*)((char*)d_ws + o_w2s);
    unsigned short* cwb = (unsigned short*)((char*)d_ws + o_cwb);
    unsigned short* xt  = (unsigned short*)((char*)d_ws + o_xt);

    build_gidx<<<NC, 1024, 0, stream>>>(M, gidx, gcnt);

    if (ws_size >= need) {
        prep_all<<<1582, 256, 0, stream>>>(X, W1, W2, cw, gidx, gcnt, xt, w1s, w2s, cwb);
        fused_mfma12<<<dim3(NB / BT, NC), 512, LDS_BYTES, stream>>>(
            xt, w1s, w2s, cwb, b1, b2, cb, protos, logvar, c_bias, gidx, gcnt, out_cl);
    } else {
        size_t smem = (size_t)(16512 + 8256 + 2112) * 4 + 32 * 4;
        fused_main<<<dim3(NB / 64, NC), 256, smem, stream>>>(
            X, W1, b1, W2, b2, cw, cb, protos, logvar, c_bias, gidx, gcnt, out_cl);
    }
    reduce_logits<<<(NB * NK + 255) / 256, 256, 0, stream>>>(out_cl, imp, bias, out_logits);
}

// Round 14
// 83.870 us; speedup vs baseline: 1.2341x; 1.0348x over previous
//
#include <hip/hip_runtime.h>
#include <hip/hip_bf16.h>

#define NB   2048
#define NG   2000
#define NC   50
#define NH   256
#define NZD  32
#define NK   10
#define NP   4
#define BT   64
#define GS   2048
#define KP   320
#define NCH  10      // KP/32

typedef short short8  __attribute__((ext_vector_type(8)));
typedef short short4v __attribute__((ext_vector_type(4)));
typedef float f32x4   __attribute__((ext_vector_type(4)));
typedef unsigned int uint2v __attribute__((ext_vector_type(2)));

__device__ __forceinline__ unsigned short f2bf(float f) {
    union { float f; unsigned u; } v; v.f = f;
    unsigned r = v.u + 0x7fffu + ((v.u >> 16) & 1u);
    return (unsigned short)(r >> 16);
}

__device__ __forceinline__ unsigned cvt_pk_bf16(float lo, float hi) {
    unsigned r;
    asm("v_cvt_pk_bf16_f32 %0, %1, %2" : "=v"(r) : "v"(lo), "v"(hi));
    return r;
}

// async 16B global->LDS (no VGPR round-trip, counted by vmcnt, in-order)
__device__ __forceinline__ void gld16(const unsigned short* g, char* l) {
    __builtin_amdgcn_global_load_lds(
        (const __attribute__((address_space(1))) unsigned int*)g,
        (__attribute__((address_space(3))) unsigned int*)l, 16, 0, 0);
}

// ---------------- deterministic ordered compaction of M (1024 thr) ---------
__global__ void build_gidx(const float* __restrict__ M, int* __restrict__ gidx,
                           int* __restrict__ gcnt) {
    int c = blockIdx.x;
    int t = threadIdx.x;
    __shared__ int wcnt[16];
    __shared__ int base;
    if (t == 0) base = 0;
    __syncthreads();
    for (int g0 = 0; g0 < NG; g0 += 1024) {
        int g = g0 + t;
        bool a = (g < NG) && (M[c * NG + g] != 0.0f);
        unsigned long long mask = __ballot(a);
        int lane = t & 63;
        int w = t >> 6;
        if (lane == 0) wcnt[w] = __popcll(mask);
        int pre = __popcll(mask & ((1ull << lane) - 1ull));
        __syncthreads();
        int woff = base;
        for (int i = 0; i < w; ++i) woff += wcnt[i];
        if (a) gidx[c * GS + woff + pre] = g;
        int tot = 0;
        #pragma unroll
        for (int i = 0; i < 16; ++i) tot += wcnt[i];
        __syncthreads();
        if (t == 0) base += tot;
        __syncthreads();
    }
    if (t == 0) gcnt[c] = base;
}

// ---------------- merged prep kernel ---------------------------------------
// blocks [0,1024): X transpose; [1024,1524): w1s; [1524,1532): w2s; [1532,1582): cwb
// w1s/w2s: fragment-order [col][32k], 16B unit q stored at q ^ ((col>>1)&3)
// cwb: [o][256h], 16B unit u stored at u ^ (o&7)
__global__ void prep_all(const float* __restrict__ X, const float* __restrict__ W1,
                         const float* __restrict__ W2, const float* __restrict__ cw,
                         const int* __restrict__ gidx, const int* __restrict__ gcnt,
                         unsigned short* __restrict__ xt, unsigned short* __restrict__ w1s,
                         unsigned short* __restrict__ w2s, unsigned short* __restrict__ cwb) {
    __shared__ float tile[64][65];
    const int bx = blockIdx.x;
    const int t  = threadIdx.x;
    if (bx < 1024) {                       // ---- xt: X^T to bf16, gene-major
        int gb = bx & 31, bb = bx >> 5;
        int tx = t & 63, tq = t >> 6;
        #pragma unroll
        for (int i = 0; i < 16; ++i) {
            int r = tq * 16 + i;
            int gene = gb * 64 + tx;
            tile[r][tx] = (gene < NG) ? X[(size_t)(bb * 64 + r) * NG + gene] : 0.f;
        }
        __syncthreads();
        #pragma unroll
        for (int i = 0; i < 16; ++i) {
            int gl = tq * 16 + i;
            int gene = gb * 64 + gl;
            if (gene < NG)
                xt[(size_t)gene * NB + bb * 64 + tx] = f2bf(tile[tx][gl]);
        }
    } else if (bx < 1524) {                // ---- w1s: gathered W1
        int idx = bx - 1024;
        int ch = idx % NCH, c = idx / NCH;
        int col = t;
        int cnt = gcnt[c]; if (cnt > KP) cnt = KP;
        unsigned short v[32];
        #pragma unroll
        for (int kin = 0; kin < 32; ++kin) {
            int k = ch * 32 + kin;
            float x = 0.f;
            if (k < cnt) {
                int g = gidx[c * GS + k];
                x = W1[(size_t)g * NH + col];
            }
            v[kin] = f2bf(x);
        }
        unsigned short* dst = w1s + (((size_t)(c * NCH + ch)) * 256 + col) * 32;
        #pragma unroll
        for (int q = 0; q < 4; ++q) {
            short8 v8;
            #pragma unroll
            for (int i = 0; i < 8; ++i) v8[i] = (short)v[q * 8 + i];
            *(short8*)(dst + (q ^ ((col >> 1) & 3)) * 8) = v8;
        }
    } else if (bx < 1532) {                // ---- w2s: W2^T chunks
        int ch = bx - 1524;
        int col = t;
        unsigned short v[32];
        #pragma unroll
        for (int kin = 0; kin < 32; ++kin)
            v[kin] = f2bf(W2[(size_t)(ch * 32 + kin) * NH + col]);
        unsigned short* dst = w2s + ((size_t)ch * 256 + col) * 32;
        #pragma unroll
        for (int q = 0; q < 4; ++q) {
            short8 v8;
            #pragma unroll
            for (int i = 0; i < 8; ++i) v8[i] = (short)v[q * 8 + i];
            *(short8*)(dst + (q ^ ((col >> 1) & 3)) * 8) = v8;
        }
    } else {                               // ---- cwb: cw -> bf16 [o][256], swizzled
        int c = bx - 1532;
        int o = t >> 3, seg = t & 7;
        #pragma unroll
        for (int blk = 0; blk < 4; ++blk) {
            int u = seg * 4 + blk;         // 16B unit (8 h's)
            short8 v8;
            #pragma unroll
            for (int i = 0; i < 8; ++i)
                v8[i] = (short)f2bf(cw[((size_t)c * NZD + o) * NH + u * 8 + i]);
            *(short8*)(cwb + (size_t)c * 8192 + o * 256 + (u ^ (o & 7)) * 8) = v8;
        }
    }
}

// ---------------- main fused kernel -----------------------------------------
// LDS (73728 B, 2 blocks/CU):
//   [0, 40960)      : X bf16 [64][320] swizzled (stage A); post-A:
//                     [0,32768) H bf16 [64][256] swizzled, [32768,40960) protos
//   [40960, 57344)  : staging buf0 (16 KB) — later SCW or SZ
//   [57344, 73728)  : staging buf1 (16 KB)
// Chunk chain j = 0..nch+8: w1s[0..nch-1], w2s[0..7], cwb. buf(j&1).
// Counted-vmcnt pipeline: one stage always in flight across the chunk body.
#define PP_OFF   32768
#define WB0      40960
#define WB1      57344
#define LDS_BYTES 73728

__global__ __launch_bounds__(512, 4) void fused_mfma13(
    const unsigned short* __restrict__ xt,
    const unsigned short* __restrict__ w1s,
    const unsigned short* __restrict__ w2s,
    const unsigned short* __restrict__ cwb,
    const float* __restrict__ b1, const float* __restrict__ b2,
    const float* __restrict__ cb, const float* __restrict__ protos,
    const float* __restrict__ logvar, const float* __restrict__ c_bias,
    const int* __restrict__ gidx, const int* __restrict__ gcnt,
    float* __restrict__ out_cl)
{
    extern __shared__ char sm[];
    const int t  = threadIdx.x;
    const int l  = t & 63;
    const int w  = t >> 6;      // 0..7
    const int lr = l & 15;
    const int lg = l >> 4;      // 0..3
    const int wb = w >> 2;      // 0..1: row block (32 rows)
    const int wh = w & 3;       // 0..3: col block (64 cols)
    const int row0 = blockIdx.x * BT;
    const int c    = blockIdx.y;
    int cnt = gcnt[c]; if (cnt > KP) cnt = KP;
    const int nch = (cnt + 31) >> 5;

    auto Hb = [&](int r, int k) -> char* {   // H bf16 [64][256] swizzled
        return sm + r * 512 + ((((k >> 3) ^ (r & 7)) << 4) | ((k & 7) << 1));
    };
    auto XLb = [&](int r, int k) -> char* {  // X bf16 [64][320] swizzled
        return sm + r * 640 + ((((k >> 3) ^ (r & 7)) << 4) | ((k & 7) << 1));
    };
    auto gsrc = [&](int j) -> const unsigned short* {
        if (j < nch)     return w1s + ((size_t)(c * NCH + j)) * 8192;
        if (j < nch + 8) return w2s + (size_t)(j - nch) * 8192;
        return cwb + (size_t)c * 8192;
    };
    auto stage_j = [&](int j) {              // 16 KB -> buf(j&1), 2 DMA/thread
        const unsigned short* g = gsrc(j);
        char* base = sm + ((j & 1) ? WB1 : WB0);
        gld16(g + t * 8,        base + t * 16);
        gld16(g + 4096 + t * 8, base + 8192 + t * 16);
    };
    auto aread = [&](int base, int col, int unit) -> short8 {
        return *(const short8*)(sm + base + col * 64 + ((unit ^ ((col >> 1) & 3)) << 4));
    };

    // ---- prologue: bias preload FIRST (oldest loads), then stages 0,1 ------
    f32x4 b1v[4], b2v[4];
    #pragma unroll
    for (int mm = 0; mm < 4; ++mm) {
        int k0 = wh * 64 + mm * 16 + lg * 4;
        b1v[mm] = *(const f32x4*)(b1 + k0);
        b2v[mm] = *(const f32x4*)(b2 + k0);
    }
    stage_j(0);
    stage_j(1);

    // ---------------- phase 0: gather ALL of Xc into LDS --------------------
    {
        const int gl2 = t & 63;         // gene-in-group
        const int rg  = t >> 6;         // row-group (8 rows)
        short8 xv[5];
        int kk[5];
        #pragma unroll
        for (int i = 0; i < 5; ++i) {
            kk[i] = i * 64 + gl2;
            xv[i] = short8{0,0,0,0,0,0,0,0};
            if (kk[i] < cnt) {
                int g = gidx[c * GS + kk[i]];
                xv[i] = *(const short8*)(xt + (size_t)g * NB + row0 + rg * 8);
            }
        }
        #pragma unroll
        for (int i = 0; i < 5; ++i)
            #pragma unroll
            for (int j = 0; j < 8; ++j)
                *(short*)XLb(rg * 8 + j, kk[i]) = xv[i][j];
    }
    asm volatile("s_waitcnt lgkmcnt(0)" ::: "memory");   // gather ds_writes done
    __builtin_amdgcn_s_barrier();
    asm volatile("" ::: "memory");

    // ---------------- stage A: h1 = leaky(Xc @ W1c + b1) --------------------
    f32x4 acc[2][4];
    #pragma unroll
    for (int nn = 0; nn < 2; ++nn)
        #pragma unroll
        for (int mm = 0; mm < 4; ++mm) acc[nn][mm] = f32x4{0.f, 0.f, 0.f, 0.f};

    for (int j = 0; j < nch; ++j) {
        asm volatile("s_waitcnt vmcnt(2)" ::: "memory"); // stage(j) landed
        __builtin_amdgcn_s_barrier();
        asm volatile("" ::: "memory");
        const int cur = (j & 1) ? WB1 : WB0;
        short8 a[4], b[2];
        #pragma unroll
        for (int mm = 0; mm < 4; ++mm)
            a[mm] = aread(cur, wh * 64 + mm * 16 + lr, lg);
        #pragma unroll
        for (int nn = 0; nn < 2; ++nn)
            b[nn] = *(const short8*)XLb(wb * 32 + nn * 16 + lr, j * 32 + lg * 8);
        #pragma unroll
        for (int nn = 0; nn < 2; ++nn)
            #pragma unroll
            for (int mm = 0; mm < 4; ++mm)
                acc[nn][mm] = __builtin_amdgcn_mfma_f32_16x16x32_bf16(a[mm], b[nn], acc[nn][mm], 0, 0, 0);
        asm volatile("s_waitcnt lgkmcnt(0)" ::: "memory"); // my LDS reads done
        __builtin_amdgcn_s_barrier();                      // all waves' reads done
        asm volatile("" ::: "memory");
        stage_j(j + 2);                    // overwrite just-read buffer (j+2<=nch+1)
    }

    // epilogue A: bias + leaky -> H (overlays X region); stages fly across
    #pragma unroll
    for (int mm = 0; mm < 4; ++mm) {
        #pragma unroll
        for (int nn = 0; nn < 2; ++nn) {
            int k0 = wh * 64 + mm * 16 + lg * 4;
            int r = wb * 32 + nn * 16 + lr;
            float v0 = acc[nn][mm][0] + b1v[mm][0]; v0 = (v0 >= 0.f) ? v0 : 0.01f * v0;
            float v1 = acc[nn][mm][1] + b1v[mm][1]; v1 = (v1 >= 0.f) ? v1 : 0.01f * v1;
            float v2 = acc[nn][mm][2] + b1v[mm][2]; v2 = (v2 >= 0.f) ? v2 : 0.01f * v2;
            float v3 = acc[nn][mm][3] + b1v[mm][3]; v3 = (v3 >= 0.f) ? v3 : 0.01f * v3;
            uint2v pk;
            pk[0] = cvt_pk_bf16(v0, v1);
            pk[1] = cvt_pk_bf16(v2, v3);
            *(uint2v*)Hb(r, k0) = pk;
        }
    }
    asm volatile("s_waitcnt lgkmcnt(0)" ::: "memory");
    __builtin_amdgcn_s_barrier();
    asm volatile("" ::: "memory");

    // ---------------- stage B: h2 = leaky(h1 @ W2 + b2) ---------------------
    f32x4 acc2[2][4];
    #pragma unroll
    for (int nn = 0; nn < 2; ++nn)
        #pragma unroll
        for (int mm = 0; mm < 4; ++mm) acc2[nn][mm] = f32x4{0.f, 0.f, 0.f, 0.f};
    for (int j = nch; j < nch + 8; ++j) {
        asm volatile("s_waitcnt vmcnt(2)" ::: "memory");
        __builtin_amdgcn_s_barrier();
        asm volatile("" ::: "memory");
        const int cur = (j & 1) ? WB1 : WB0;
        const int ch = j - nch;
        short8 a[4], b[2];
        #pragma unroll
        for (int mm = 0; mm < 4; ++mm)
            a[mm] = aread(cur, wh * 64 + mm * 16 + lr, lg);
        #pragma unroll
        for (int nn = 0; nn < 2; ++nn)
            b[nn] = *(const short8*)Hb(wb * 32 + nn * 16 + lr, ch * 32 + lg * 8);
        #pragma unroll
        for (int nn = 0; nn < 2; ++nn)
            #pragma unroll
            for (int mm = 0; mm < 4; ++mm)
                acc2[nn][mm] = __builtin_amdgcn_mfma_f32_16x16x32_bf16(a[mm], b[nn], acc2[nn][mm], 0, 0, 0);
        asm volatile("s_waitcnt lgkmcnt(0)" ::: "memory");
        __builtin_amdgcn_s_barrier();
        asm volatile("" ::: "memory");
        if (j + 2 <= nch + 8) stage_j(j + 2);
    }
    const int cwbase = ((nch + 8) & 1) ? WB1 : WB0;
    const int szbase = ((nch + 8) & 1) ? WB0 : WB1;

    // epilogue B: h2 -> H (overwrite) + stage protos/i2e/cbias
    {
        #pragma unroll
        for (int mm = 0; mm < 4; ++mm) {
            #pragma unroll
            for (int nn = 0; nn < 2; ++nn) {
                int k0 = wh * 64 + mm * 16 + lg * 4;
                int r = wb * 32 + nn * 16 + lr;
                float v0 = acc2[nn][mm][0] + b2v[mm][0]; v0 = (v0 >= 0.f) ? v0 : 0.01f * v0;
                float v1 = acc2[nn][mm][1] + b2v[mm][1]; v1 = (v1 >= 0.f) ? v1 : 0.01f * v1;
                float v2 = acc2[nn][mm][2] + b2v[mm][2]; v2 = (v2 >= 0.f) ? v2 : 0.01f * v2;
                float v3 = acc2[nn][mm][3] + b2v[mm][3]; v3 = (v3 >= 0.f) ? v3 : 0.01f * v3;
                uint2v pk;
                pk[0] = cvt_pk_bf16(v0, v1);
                pk[1] = cvt_pk_bf16(v2, v3);
                *(uint2v*)Hb(r, k0) = pk;
            }
        }
        float* pp = (float*)(sm + PP_OFF);
        for (int i = t; i < NK * NP * NZD; i += 512)
            pp[(i >> 5) * 36 + (i & 31)] = protos[(size_t)c * (NK * NP * NZD) + i];
        if (t < NK * NP) pp[1440 + t] = 0.5f * expf(-logvar[c * (NK * NP) + t]);
        if (t < NK)      pp[1480 + t] = c_bias[c * NK + t];
    }
    __syncthreads();   // full drain: cw stage + proto loads + H/proto writes

    // ---------------- stage C: Z = h2 @ cw^T + cb (all 8 waves, LDS-fed) ----
    {
        const int rt = w & 3, ot = w >> 2;
        const int o = ot * 16 + lr;
        f32x4 az = f32x4{0.f, 0.f, 0.f, 0.f};
        #pragma unroll
        for (int ch = 0; ch < 8; ++ch) {
            short8 afr = *(const short8*)(sm + cwbase + o * 512 +
                                          ((((ch << 2) + lg) ^ (o & 7)) << 4));
            short8 bfr = *(const short8*)Hb(rt * 16 + lr, ch * 32 + lg * 8);
            az = __builtin_amdgcn_mfma_f32_16x16x32_bf16(afr, bfr, az, 0, 0, 0);
        }
        f32x4 cb4 = *(const f32x4*)(cb + c * NZD + ot * 16 + lg * 4);
        float* SZ = (float*)(sm + szbase);
        #pragma unroll
        for (int i = 0; i < 4; ++i)
            SZ[(rt * 16 + lr) * 36 + ot * 16 + lg * 4 + i] = az[i] + cb4[i];
    }
    __syncthreads();

    // ---------------- stage D: prototype distances -> c_logits --------------
    {
        const float* SZ  = (const float*)(sm + szbase);
        const float* pp  = (const float*)(sm + PP_OFF);
        const float* i2e = pp + 1440;
        const float* cbs = pp + 1480;
        const int rloc = (w & 3) * 16 + lr;
        f32x4 z[8];
        #pragma unroll
        for (int j = 0; j < 8; ++j)
            z[j] = *(const f32x4*)(SZ + rloc * 36 + j * 4);
        const int kk0 = (w >> 2) * 5;
        #pragma unroll
        for (int kk = kk0; kk < kk0 + 5; ++kk) {
            int kp = kk * NP + lg;       // lg == p
            f32x4 d = f32x4{0.f, 0.f, 0.f, 0.f};
            #pragma unroll
            for (int j = 0; j < 8; ++j) {
                f32x4 p = *(const f32x4*)(pp + kp * 36 + j * 4);
                f32x4 df = z[j] - p;
                d += df * df;
            }
            float sc = ((d[0] + d[1]) + (d[2] + d[3])) * i2e[kp];
            sc = fminf(sc, __shfl_xor(sc, 16));
            sc = fminf(sc, __shfl_xor(sc, 32));
            if (lg == 0)
                out_cl[((size_t)(row0 + rloc) * NC + c) * NK + kk] = cbs[kk] - sc;
        }
    }
}

// ---------------- fallback (round-1 fp32 path, known-good) -----------------
__global__ __launch_bounds__(256, 1) void fused_main(
    const float* __restrict__ X,  const float* __restrict__ W1,
    const float* __restrict__ b1, const float* __restrict__ W2,
    const float* __restrict__ b2, const float* __restrict__ cw,
    const float* __restrict__ cb, const float* __restrict__ protos,
    const float* __restrict__ logvar, const float* __restrict__ c_bias,
    const int* __restrict__ gidx, const int* __restrict__ gcnt,
    float* __restrict__ out_cl)
{
    extern __shared__ float smemf[];
    float (*sh_big)[258] = (float (*)[258])smemf;
    float (*sh_w)[258]   = (float (*)[258])(smemf + 16512);
    float (*sh_x)[33]    = (float (*)[33])(smemf + 16512 + 8256);
    int*  sh_gid         = (int*)(smemf + 16512 + 8256 + 2112);

    const int t   = threadIdx.x;
    const int tx  = t & 15;
    const int ty  = t >> 4;
    const int row0 = blockIdx.x * 64;
    const int c    = blockIdx.y;

    float acc[4][16];
    #pragma unroll
    for (int i = 0; i < 4; ++i)
        #pragma unroll
        for (int l = 0; l < 16; ++l) acc[i][l] = 0.f;

    const int cnt = gcnt[c];
    const int nch = (cnt + 31) >> 5;
    for (int ch = 0; ch < nch; ++ch) {
        __syncthreads();
        if (t < 32) {
            int gi = ch * 32 + t;
            sh_gid[t] = (gi < cnt) ? gidx[c * GS + gi] : -1;
        }
        __syncthreads();
        #pragma unroll 4
        for (int jj = 0; jj < 32; ++jj) {
            int g = sh_gid[jj];
            sh_w[jj][t] = (g >= 0) ? W1[g * NH + t] : 0.f;
        }
        {
            int j  = t & 31;
            int rb2 = (t >> 5) * 8;
            int g  = sh_gid[j];
            #pragma unroll
            for (int ii = 0; ii < 8; ++ii)
                sh_x[rb2 + ii][j] = (g >= 0) ? X[(size_t)(row0 + rb2 + ii) * NG + g] : 0.f;
        }
        __syncthreads();
        #pragma unroll 8
        for (int j = 0; j < 32; ++j) {
            float xv[4];
            #pragma unroll
            for (int i = 0; i < 4; ++i) xv[i] = sh_x[ty * 4 + i][j];
            #pragma unroll
            for (int l = 0; l < 16; ++l) {
                float wv = sh_w[j][l * 16 + tx];
                #pragma unroll
                for (int i = 0; i < 4; ++i) acc[i][l] = fmaf(xv[i], wv, acc[i][l]);
            }
        }
    }
    #pragma unroll
    for (int i = 0; i < 4; ++i)
        #pragma unroll
        for (int l = 0; l < 16; ++l) {
            int col = l * 16 + tx;
            float v = acc[i][l] + b1[col];
            sh_big[ty * 4 + i][col] = (v >= 0.f) ? v : 0.01f * v;
        }

    float acc2[4][16];
    #pragma unroll
    for (int i = 0; i < 4; ++i)
        #pragma unroll
        for (int l = 0; l < 16; ++l) acc2[i][l] = 0.f;
    for (int ch = 0; ch < NH / 32; ++ch) {
        __syncthreads();
        #pragma unroll 4
        for (int jj = 0; jj < 32; ++jj)
            sh_w[jj][t] = W2[(size_t)(ch * 32 + jj) * NH + t];
        __syncthreads();
        #pragma unroll 8
        for (int j = 0; j < 32; ++j) {
            float xv[4];
            #pragma unroll
            for (int i = 0; i < 4; ++i) xv[i] = sh_big[ty * 4 + i][ch * 32 + j];
            #pragma unroll
            for (int l = 0; l < 16; ++l) {
                float wv = sh_w[j][l * 16 + tx];
                #pragma unroll
                for (int i = 0; i < 4; ++i) acc2[i][l] = fmaf(xv[i], wv, acc2[i][l]);
            }
        }
    }
    __syncthreads();
    #pragma unroll
    for (int i = 0; i < 4; ++i)
        #pragma unroll
        for (int l = 0; l < 16; ++l) {
            int col = l * 16 + tx;
            float v = acc2[i][l] + b2[col];
            sh_big[ty * 4 + i][col] = (v >= 0.f) ? v : 0.01f * v;
        }
    #pragma unroll 4
    for (int o = 0; o < NZD; ++o)
        sh_w[o][t] = cw[((size_t)c * NZD + o) * NH + t];
    __syncthreads();
    {
        int o  = t & 31;
        int rg = t >> 5;
        float cbv = cb[c * NZD + o];
        float zv[8];
        #pragma unroll
        for (int i = 0; i < 8; ++i) zv[i] = cbv;
        for (int h = 0; h < NH; ++h) {
            float wv = sh_w[o][h];
            #pragma unroll
            for (int i = 0; i < 8; ++i)
                zv[i] = fmaf(sh_big[rg * 8 + i][h], wv, zv[i]);
        }
        #pragma unroll
        for (int i = 0; i < 8; ++i) sh_x[rg * 8 + i][o] = zv[i];
    }
    __syncthreads();
    float* proto_s = &sh_w[0][0];
    float* i2e_s   = proto_s + NK * NP * NZD;
    float* cbias_s = i2e_s + NK * NP;
    for (int i = t; i < NK * NP * NZD; i += 256)
        proto_s[i] = protos[(size_t)c * NK * NP * NZD + i];
    if (t < NK * NP) i2e_s[t] = 0.5f * expf(-logvar[c * NK * NP + t]);
    if (t < NK)      cbias_s[t] = c_bias[c * NK + t];
    __syncthreads();
    for (int task = t; task < 64 * NK; task += 256) {
        int r = task / NK;
        int k = task - r * NK;
        float best = 3.4e38f;
        #pragma unroll
        for (int p = 0; p < NP; ++p) {
            float d2 = 0.f;
            const float* ppr = proto_s + (k * NP + p) * NZD;
            #pragma unroll
            for (int o = 0; o < NZD; ++o) {
                float dv = sh_x[r][o] - ppr[o];
                d2 = fmaf(dv, dv, d2);
            }
            float sc = d2 * i2e_s[k * NP + p];
            best = fminf(best, sc);
        }
        out_cl[((size_t)(row0 + r) * NC + c) * NK + k] = cbias_s[k] - best;
    }
}

// ---------------- logits reduce ---------------------------------------------
__global__ void reduce_logits(const float* __restrict__ cl,
                              const float* __restrict__ importance,
                              const float* __restrict__ bias,
                              float* __restrict__ out) {
    int idx = blockIdx.x * blockDim.x + threadIdx.x;
    if (idx >= NB * NK) return;
    int b = idx / NK;
    int k = idx - b * NK;
    float s = 0.f;
    #pragma unroll
    for (int c = 0; c < NC; ++c) {
        float imp = fabsf(importance[c]);
        s += expf(cl[((size_t)b * NC + c) * NK + k]) * imp + 1e-16f;
    }
    out[idx] = logf(s) + bias[k];
}

extern "C" void kernel_launch(void* const* d_in, const int* in_sizes, int n_in,
                              void* d_out, int out_size, void* d_ws, size_t ws_size,
                              hipStream_t stream) {
    const float* X      = (const float*)d_in[0];
    const float* M      = (const float*)d_in[1];
    const float* W1     = (const float*)d_in[2];
    const float* b1     = (const float*)d_in[3];
    const float* W2     = (const float*)d_in[4];
    const float* b2     = (const float*)d_in[5];
    const float* cw     = (const float*)d_in[6];
    const float* cb     = (const float*)d_in[7];
    const float* protos = (const float*)d_in[8];
    const float* logvar = (const float*)d_in[9];
    const float* c_bias = (const float*)d_in[10];
    const float* bias   = (const float*)d_in[11];
    const float* imp    = (const float*)d_in[12];

    float* out_logits = (float*)d_out;
    float* out_cl     = out_logits + NB * NK;

    // workspace layout (bytes)
    const size_t o_gcnt = (size_t)NC * GS * 4;
    const size_t o_w1s  = o_gcnt + 256;
    const size_t o_w2s  = o_w1s + (size_t)NC * NCH * 256 * 32 * 2;
    const size_t o_cwb  = o_w2s + (size_t)8 * 256 * 32 * 2;
    const size_t o_xt   = o_cwb + (size_t)NC * 32 * 256 * 2;
    const size_t need   = o_xt + (size_t)NG * NB * 2;

    int* gidx = (int*)d_ws;
    int* gcnt = (int*)((char*)d_ws + o_gcnt);
    unsigned short* w1s = (unsigned short*)((char*)d_ws + o_w1s);
    unsigned short* w2s = (unsigned short*)((char*)d_ws + o_w2s);
    unsigned short* cwb = (unsigned short*)((char*)d_ws + o_cwb);
    unsigned short* xt  = (unsigned short*)((char*)d_ws + o_xt);

    build_gidx<<<NC, 1024, 0, stream>>>(M, gidx, gcnt);

    if (ws_size >= need) {
        prep_all<<<1582, 256, 0, stream>>>(X, W1, W2, cw, gidx, gcnt, xt, w1s, w2s, cwb);
        fused_mfma13<<<dim3(NB / BT, NC), 512, LDS_BYTES, stream>>>(
            xt, w1s, w2s, cwb, b1, b2, cb, protos, logvar, c_bias, gidx, gcnt, out_cl);
    } else {
        size_t smem = (size_t)(16512 + 8256 + 2112) * 4 + 32 * 4;
        fused_main<<<dim3(NB / 64, NC), 256, smem, stream>>>(
            X, W1, b1, W2, b2, cw, cb, protos, logvar, c_bias, gidx, gcnt, out_cl);
    }
    reduce_logits<<<(NB * NK + 255) / 256, 256, 0, stream>>>(out_cl, imp, bias, out_logits);
}

// Round 15
// 80.156 us; speedup vs baseline: 1.2913x; 1.0463x over previous
//
#include <hip/hip_runtime.h>
#include <hip/hip_bf16.h>

#define NB   2048
#define NG   2000
#define NC   50
#define NH   256
#define NZD  32
#define NK   10
#define NP   4
#define BT   64
#define GS   2048
#define KP   320
#define NCH  10      // KP/32

typedef short short8  __attribute__((ext_vector_type(8)));
typedef short short4v __attribute__((ext_vector_type(4)));
typedef float f32x4   __attribute__((ext_vector_type(4)));
typedef unsigned int uint2v __attribute__((ext_vector_type(2)));

__device__ __forceinline__ unsigned short f2bf(float f) {
    union { float f; unsigned u; } v; v.f = f;
    unsigned r = v.u + 0x7fffu + ((v.u >> 16) & 1u);
    return (unsigned short)(r >> 16);
}

__device__ __forceinline__ unsigned cvt_pk_bf16(float lo, float hi) {
    unsigned r;
    asm("v_cvt_pk_bf16_f32 %0, %1, %2" : "=v"(r) : "v"(lo), "v"(hi));
    return r;
}

// async 16B global->LDS (no VGPR round-trip, counted by vmcnt, in-order)
__device__ __forceinline__ void gld16(const unsigned short* g, char* l) {
    __builtin_amdgcn_global_load_lds(
        (const __attribute__((address_space(1))) unsigned int*)g,
        (__attribute__((address_space(3))) unsigned int*)l, 16, 0, 0);
}

// ---------------- fallback-only: ordered compaction of M -------------------
__global__ void build_gidx(const float* __restrict__ M, int* __restrict__ gidx,
                           int* __restrict__ gcnt) {
    int c = blockIdx.x;
    int t = threadIdx.x;
    __shared__ int wcnt[16];
    __shared__ int base;
    if (t == 0) base = 0;
    __syncthreads();
    for (int g0 = 0; g0 < NG; g0 += 1024) {
        int g = g0 + t;
        bool a = (g < NG) && (M[c * NG + g] != 0.0f);
        unsigned long long mask = __ballot(a);
        int lane = t & 63;
        int w = t >> 6;
        if (lane == 0) wcnt[w] = __popcll(mask);
        int pre = __popcll(mask & ((1ull << lane) - 1ull));
        __syncthreads();
        int woff = base;
        for (int i = 0; i < w; ++i) woff += wcnt[i];
        if (a) gidx[c * GS + woff + pre] = g;
        int tot = 0;
        #pragma unroll
        for (int i = 0; i < 16; ++i) tot += wcnt[i];
        __syncthreads();
        if (t == 0) base += tot;
        __syncthreads();
    }
    if (t == 0) gcnt[c] = base;
}

// ---------------- merged prep kernel (now also builds gidx) ----------------
// blocks [0,1024): X transpose; [1024,1524): w1s (+gidx for ch==0);
// [1524,1532): w2s; [1532,1582): cwb
// w1s/w2s: fragment-order [col][32k], 16B unit q stored at q ^ ((col>>1)&3)
// cwb: [o][256h], 16B unit u stored at u ^ (o&7)
__global__ void prep_all(const float* __restrict__ X, const float* __restrict__ W1,
                         const float* __restrict__ W2, const float* __restrict__ cw,
                         const float* __restrict__ M,
                         int* __restrict__ gidx, int* __restrict__ gcnt,
                         unsigned short* __restrict__ xt, unsigned short* __restrict__ w1s,
                         unsigned short* __restrict__ w2s, unsigned short* __restrict__ cwb) {
    __shared__ float tile[64][65];
    const int bx = blockIdx.x;
    const int t  = threadIdx.x;
    if (bx < 1024) {                       // ---- xt: X^T to bf16, gene-major
        int gb = bx & 31, bb = bx >> 5;
        int tx = t & 63, tq = t >> 6;
        #pragma unroll
        for (int i = 0; i < 16; ++i) {
            int r = tq * 16 + i;
            int gene = gb * 64 + tx;
            tile[r][tx] = (gene < NG) ? X[(size_t)(bb * 64 + r) * NG + gene] : 0.f;
        }
        __syncthreads();
        #pragma unroll
        for (int i = 0; i < 16; ++i) {
            int gl = tq * 16 + i;
            int gene = gb * 64 + gl;
            if (gene < NG)
                xt[(size_t)gene * NB + bb * 64 + tx] = f2bf(tile[tx][gl]);
        }
    } else if (bx < 1524) {                // ---- w1s: gathered W1, self-scan
        int idx = bx - 1024;
        int ch = idx % NCH, c = idx / NCH;
        // each thread owns genes [t*8, t*8+8); ordered scan of M[c,:]
        __shared__ int psum[256];
        __shared__ int myGenes[32];
        __shared__ int totcnt;
        int own[8];
        int cl = 0;
        #pragma unroll
        for (int i = 0; i < 8; ++i) {
            int g = t * 8 + i;
            bool a = (g < NG) && (M[(size_t)c * NG + g] != 0.f);
            own[i] = a ? g : -1;
            cl += a ? 1 : 0;
        }
        psum[t] = cl;
        __syncthreads();
        for (int off = 1; off < 256; off <<= 1) {
            int v = psum[t];
            int u = (t >= off) ? psum[t - off] : 0;
            __syncthreads();
            psum[t] = v + u;
            __syncthreads();
        }
        int base = psum[t] - cl;          // exclusive prefix
        if (t == 255) totcnt = psum[255];
        __syncthreads();
        int cnt = totcnt; if (cnt > KP) cnt = KP;
        {
            int pos = base;
            #pragma unroll
            for (int i = 0; i < 8; ++i) {
                if (own[i] >= 0) {
                    int rel = pos - ch * 32;
                    if (rel >= 0 && rel < 32) myGenes[rel] = own[i];
                    ++pos;
                }
            }
        }
        if (ch == 0) {                    // designated block: emit gidx/gcnt
            int pos = base;
            #pragma unroll
            for (int i = 0; i < 8; ++i)
                if (own[i] >= 0) { gidx[c * GS + pos] = own[i]; ++pos; }
            if (t == 255) gcnt[c] = totcnt;
        }
        __syncthreads();
        int col = t;
        unsigned short v[32];
        #pragma unroll
        for (int kin = 0; kin < 32; ++kin) {
            int k = ch * 32 + kin;
            float x = 0.f;
            if (k < cnt) {
                int g = myGenes[kin];
                x = W1[(size_t)g * NH + col];
            }
            v[kin] = f2bf(x);
        }
        unsigned short* dst = w1s + (((size_t)(c * NCH + ch)) * 256 + col) * 32;
        #pragma unroll
        for (int q = 0; q < 4; ++q) {
            short8 v8;
            #pragma unroll
            for (int i = 0; i < 8; ++i) v8[i] = (short)v[q * 8 + i];
            *(short8*)(dst + (q ^ ((col >> 1) & 3)) * 8) = v8;
        }
    } else if (bx < 1532) {                // ---- w2s: W2^T chunks
        int ch = bx - 1524;
        int col = t;
        unsigned short v[32];
        #pragma unroll
        for (int kin = 0; kin < 32; ++kin)
            v[kin] = f2bf(W2[(size_t)(ch * 32 + kin) * NH + col]);
        unsigned short* dst = w2s + ((size_t)ch * 256 + col) * 32;
        #pragma unroll
        for (int q = 0; q < 4; ++q) {
            short8 v8;
            #pragma unroll
            for (int i = 0; i < 8; ++i) v8[i] = (short)v[q * 8 + i];
            *(short8*)(dst + (q ^ ((col >> 1) & 3)) * 8) = v8;
        }
    } else {                               // ---- cwb: cw -> bf16 [o][256], swizzled
        int c = bx - 1532;
        int o = t >> 3, seg = t & 7;
        #pragma unroll
        for (int blk = 0; blk < 4; ++blk) {
            int u = seg * 4 + blk;         // 16B unit (8 h's)
            short8 v8;
            #pragma unroll
            for (int i = 0; i < 8; ++i)
                v8[i] = (short)f2bf(cw[((size_t)c * NZD + o) * NH + u * 8 + i]);
            *(short8*)(cwb + (size_t)c * 8192 + o * 256 + (u ^ (o & 7)) * 8) = v8;
        }
    }
}

// ---------------- main fused kernel (R14 structure, unchanged) --------------
// LDS (73728 B, 2 blocks/CU):
//   [0, 40960)      : X bf16 [64][320] swizzled (stage A); post-A:
//                     [0,32768) H bf16 [64][256] swizzled, [32768,40960) protos
//   [40960, 57344)  : staging buf0 (16 KB) — later SCW or SZ
//   [57344, 73728)  : staging buf1 (16 KB)
// Chunk chain j = 0..nch+8: w1s[0..nch-1], w2s[0..7], cwb. buf(j&1).
#define PP_OFF   32768
#define WB0      40960
#define WB1      57344
#define LDS_BYTES 73728

__global__ __launch_bounds__(512, 4) void fused_mfma14(
    const unsigned short* __restrict__ xt,
    const unsigned short* __restrict__ w1s,
    const unsigned short* __restrict__ w2s,
    const unsigned short* __restrict__ cwb,
    const float* __restrict__ b1, const float* __restrict__ b2,
    const float* __restrict__ cb, const float* __restrict__ protos,
    const float* __restrict__ logvar, const float* __restrict__ c_bias,
    const int* __restrict__ gidx, const int* __restrict__ gcnt,
    float* __restrict__ out_cl)
{
    extern __shared__ char sm[];
    const int t  = threadIdx.x;
    const int l  = t & 63;
    const int w  = t >> 6;      // 0..7
    const int lr = l & 15;
    const int lg = l >> 4;      // 0..3
    const int wb = w >> 2;      // 0..1: row block (32 rows)
    const int wh = w & 3;       // 0..3: col block (64 cols)
    const int row0 = blockIdx.x * BT;
    const int c    = blockIdx.y;
    int cnt = gcnt[c]; if (cnt > KP) cnt = KP;
    const int nch = (cnt + 31) >> 5;

    auto Hb = [&](int r, int k) -> char* {   // H bf16 [64][256] swizzled
        return sm + r * 512 + ((((k >> 3) ^ (r & 7)) << 4) | ((k & 7) << 1));
    };
    auto XLb = [&](int r, int k) -> char* {  // X bf16 [64][320] swizzled
        return sm + r * 640 + ((((k >> 3) ^ (r & 7)) << 4) | ((k & 7) << 1));
    };
    auto gsrc = [&](int j) -> const unsigned short* {
        if (j < nch)     return w1s + ((size_t)(c * NCH + j)) * 8192;
        if (j < nch + 8) return w2s + (size_t)(j - nch) * 8192;
        return cwb + (size_t)c * 8192;
    };
    auto stage_j = [&](int j) {              // 16 KB -> buf(j&1), 2 DMA/thread
        const unsigned short* g = gsrc(j);
        char* base = sm + ((j & 1) ? WB1 : WB0);
        gld16(g + t * 8,        base + t * 16);
        gld16(g + 4096 + t * 8, base + 8192 + t * 16);
    };
    auto aread = [&](int base, int col, int unit) -> short8 {
        return *(const short8*)(sm + base + col * 64 + ((unit ^ ((col >> 1) & 3)) << 4));
    };

    // ---- prologue: bias preload FIRST (oldest loads), then stages 0,1 ------
    f32x4 b1v[4], b2v[4];
    #pragma unroll
    for (int mm = 0; mm < 4; ++mm) {
        int k0 = wh * 64 + mm * 16 + lg * 4;
        b1v[mm] = *(const f32x4*)(b1 + k0);
        b2v[mm] = *(const f32x4*)(b2 + k0);
    }
    stage_j(0);
    stage_j(1);

    // ---------------- phase 0: gather ALL of Xc into LDS --------------------
    {
        const int gl2 = t & 63;         // gene-in-group
        const int rg  = t >> 6;         // row-group (8 rows)
        short8 xv[5];
        int kk[5];
        #pragma unroll
        for (int i = 0; i < 5; ++i) {
            kk[i] = i * 64 + gl2;
            xv[i] = short8{0,0,0,0,0,0,0,0};
            if (kk[i] < cnt) {
                int g = gidx[c * GS + kk[i]];
                xv[i] = *(const short8*)(xt + (size_t)g * NB + row0 + rg * 8);
            }
        }
        #pragma unroll
        for (int i = 0; i < 5; ++i)
            #pragma unroll
            for (int j = 0; j < 8; ++j)
                *(short*)XLb(rg * 8 + j, kk[i]) = xv[i][j];
    }
    asm volatile("s_waitcnt lgkmcnt(0)" ::: "memory");   // gather ds_writes done
    __builtin_amdgcn_s_barrier();
    asm volatile("" ::: "memory");

    // ---------------- stage A: h1 = leaky(Xc @ W1c + b1) --------------------
    f32x4 acc[2][4];
    #pragma unroll
    for (int nn = 0; nn < 2; ++nn)
        #pragma unroll
        for (int mm = 0; mm < 4; ++mm) acc[nn][mm] = f32x4{0.f, 0.f, 0.f, 0.f};

    for (int j = 0; j < nch; ++j) {
        asm volatile("s_waitcnt vmcnt(2)" ::: "memory"); // stage(j) landed
        __builtin_amdgcn_s_barrier();
        asm volatile("" ::: "memory");
        const int cur = (j & 1) ? WB1 : WB0;
        short8 a[4], b[2];
        #pragma unroll
        for (int mm = 0; mm < 4; ++mm)
            a[mm] = aread(cur, wh * 64 + mm * 16 + lr, lg);
        #pragma unroll
        for (int nn = 0; nn < 2; ++nn)
            b[nn] = *(const short8*)XLb(wb * 32 + nn * 16 + lr, j * 32 + lg * 8);
        #pragma unroll
        for (int nn = 0; nn < 2; ++nn)
            #pragma unroll
            for (int mm = 0; mm < 4; ++mm)
                acc[nn][mm] = __builtin_amdgcn_mfma_f32_16x16x32_bf16(a[mm], b[nn], acc[nn][mm], 0, 0, 0);
        asm volatile("s_waitcnt lgkmcnt(0)" ::: "memory"); // my LDS reads done
        __builtin_amdgcn_s_barrier();                      // all waves' reads done
        asm volatile("" ::: "memory");
        stage_j(j + 2);                    // overwrite just-read buffer (j+2<=nch+1)
    }

    // epilogue A: bias + leaky -> H (overlays X region); stages fly across
    #pragma unroll
    for (int mm = 0; mm < 4; ++mm) {
        #pragma unroll
        for (int nn = 0; nn < 2; ++nn) {
            int k0 = wh * 64 + mm * 16 + lg * 4;
            int r = wb * 32 + nn * 16 + lr;
            float v0 = acc[nn][mm][0] + b1v[mm][0]; v0 = (v0 >= 0.f) ? v0 : 0.01f * v0;
            float v1 = acc[nn][mm][1] + b1v[mm][1]; v1 = (v1 >= 0.f) ? v1 : 0.01f * v1;
            float v2 = acc[nn][mm][2] + b1v[mm][2]; v2 = (v2 >= 0.f) ? v2 : 0.01f * v2;
            float v3 = acc[nn][mm][3] + b1v[mm][3]; v3 = (v3 >= 0.f) ? v3 : 0.01f * v3;
            uint2v pk;
            pk[0] = cvt_pk_bf16(v0, v1);
            pk[1] = cvt_pk_bf16(v2, v3);
            *(uint2v*)Hb(r, k0) = pk;
        }
    }
    asm volatile("s_waitcnt lgkmcnt(0)" ::: "memory");
    __builtin_amdgcn_s_barrier();
    asm volatile("" ::: "memory");

    // ---------------- stage B: h2 = leaky(h1 @ W2 + b2) ---------------------
    f32x4 acc2[2][4];
    #pragma unroll
    for (int nn = 0; nn < 2; ++nn)
        #pragma unroll
        for (int mm = 0; mm < 4; ++mm) acc2[nn][mm] = f32x4{0.f, 0.f, 0.f, 0.f};
    for (int j = nch; j < nch + 8; ++j) {
        asm volatile("s_waitcnt vmcnt(2)" ::: "memory");
        __builtin_amdgcn_s_barrier();
        asm volatile("" ::: "memory");
        const int cur = (j & 1) ? WB1 : WB0;
        const int ch = j - nch;
        short8 a[4], b[2];
        #pragma unroll
        for (int mm = 0; mm < 4; ++mm)
            a[mm] = aread(cur, wh * 64 + mm * 16 + lr, lg);
        #pragma unroll
        for (int nn = 0; nn < 2; ++nn)
            b[nn] = *(const short8*)Hb(wb * 32 + nn * 16 + lr, ch * 32 + lg * 8);
        #pragma unroll
        for (int nn = 0; nn < 2; ++nn)
            #pragma unroll
            for (int mm = 0; mm < 4; ++mm)
                acc2[nn][mm] = __builtin_amdgcn_mfma_f32_16x16x32_bf16(a[mm], b[nn], acc2[nn][mm], 0, 0, 0);
        asm volatile("s_waitcnt lgkmcnt(0)" ::: "memory");
        __builtin_amdgcn_s_barrier();
        asm volatile("" ::: "memory");
        if (j + 2 <= nch + 8) stage_j(j + 2);
    }
    const int cwbase = ((nch + 8) & 1) ? WB1 : WB0;
    const int szbase = ((nch + 8) & 1) ? WB0 : WB1;

    // epilogue B: h2 -> H (overwrite) + stage protos/i2e/cbias
    {
        #pragma unroll
        for (int mm = 0; mm < 4; ++mm) {
            #pragma unroll
            for (int nn = 0; nn < 2; ++nn) {
                int k0 = wh * 64 + mm * 16 + lg * 4;
                int r = wb * 32 + nn * 16 + lr;
                float v0 = acc2[nn][mm][0] + b2v[mm][0]; v0 = (v0 >= 0.f) ? v0 : 0.01f * v0;
                float v1 = acc2[nn][mm][1] + b2v[mm][1]; v1 = (v1 >= 0.f) ? v1 : 0.01f * v1;
                float v2 = acc2[nn][mm][2] + b2v[mm][2]; v2 = (v2 >= 0.f) ? v2 : 0.01f * v2;
                float v3 = acc2[nn][mm][3] + b2v[mm][3]; v3 = (v3 >= 0.f) ? v3 : 0.01f * v3;
                uint2v pk;
                pk[0] = cvt_pk_bf16(v0, v1);
                pk[1] = cvt_pk_bf16(v2, v3);
                *(uint2v*)Hb(r, k0) = pk;
            }
        }
        float* pp = (float*)(sm + PP_OFF);
        for (int i = t; i < NK * NP * NZD; i += 512)
            pp[(i >> 5) * 36 + (i & 31)] = protos[(size_t)c * (NK * NP * NZD) + i];
        if (t < NK * NP) pp[1440 + t] = 0.5f * expf(-logvar[c * (NK * NP) + t]);
        if (t < NK)      pp[1480 + t] = c_bias[c * NK + t];
    }
    __syncthreads();   // full drain: cw stage + proto loads + H/proto writes

    // ---------------- stage C: Z = h2 @ cw^T + cb (all 8 waves, LDS-fed) ----
    {
        const int rt = w & 3, ot = w >> 2;
        const int o = ot * 16 + lr;
        f32x4 az = f32x4{0.f, 0.f, 0.f, 0.f};
        #pragma unroll
        for (int ch = 0; ch < 8; ++ch) {
            short8 afr = *(const short8*)(sm + cwbase + o * 512 +
                                          ((((ch << 2) + lg) ^ (o & 7)) << 4));
            short8 bfr = *(const short8*)Hb(rt * 16 + lr, ch * 32 + lg * 8);
            az = __builtin_amdgcn_mfma_f32_16x16x32_bf16(afr, bfr, az, 0, 0, 0);
        }
        f32x4 cb4 = *(const f32x4*)(cb + c * NZD + ot * 16 + lg * 4);
        float* SZ = (float*)(sm + szbase);
        #pragma unroll
        for (int i = 0; i < 4; ++i)
            SZ[(rt * 16 + lr) * 36 + ot * 16 + lg * 4 + i] = az[i] + cb4[i];
    }
    __syncthreads();

    // ---------------- stage D: prototype distances -> c_logits --------------
    {
        const float* SZ  = (const float*)(sm + szbase);
        const float* pp  = (const float*)(sm + PP_OFF);
        const float* i2e = pp + 1440;
        const float* cbs = pp + 1480;
        const int rloc = (w & 3) * 16 + lr;
        f32x4 z[8];
        #pragma unroll
        for (int j = 0; j < 8; ++j)
            z[j] = *(const f32x4*)(SZ + rloc * 36 + j * 4);
        const int kk0 = (w >> 2) * 5;
        #pragma unroll
        for (int kk = kk0; kk < kk0 + 5; ++kk) {
            int kp = kk * NP + lg;       // lg == p
            f32x4 d = f32x4{0.f, 0.f, 0.f, 0.f};
            #pragma unroll
            for (int j = 0; j < 8; ++j) {
                f32x4 p = *(const f32x4*)(pp + kp * 36 + j * 4);
                f32x4 df = z[j] - p;
                d += df * df;
            }
            float sc = ((d[0] + d[1]) + (d[2] + d[3])) * i2e[kp];
            sc = fminf(sc, __shfl_xor(sc, 16));
            sc = fminf(sc, __shfl_xor(sc, 32));
            if (lg == 0)
                out_cl[((size_t)(row0 + rloc) * NC + c) * NK + kk] = cbs[kk] - sc;
        }
    }
}

// ---------------- fallback (round-1 fp32 path, known-good) -----------------
__global__ __launch_bounds__(256, 1) void fused_main(
    const float* __restrict__ X,  const float* __restrict__ W1,
    const float* __restrict__ b1, const float* __restrict__ W2,
    const float* __restrict__ b2, const float* __restrict__ cw,
    const float* __restrict__ cb, const float* __restrict__ protos,
    const float* __restrict__ logvar, const float* __restrict__ c_bias,
    const int* __restrict__ gidx, const int* __restrict__ gcnt,
    float* __restrict__ out_cl)
{
    extern __shared__ float smemf[];
    float (*sh_big)[258] = (float (*)[258])smemf;
    float (*sh_w)[258]   = (float (*)[258])(smemf + 16512);
    float (*sh_x)[33]    = (float (*)[33])(smemf + 16512 + 8256);
    int*  sh_gid         = (int*)(smemf + 16512 + 8256 + 2112);

    const int t   = threadIdx.x;
    const int tx  = t & 15;
    const int ty  = t >> 4;
    const int row0 = blockIdx.x * 64;
    const int c    = blockIdx.y;

    float acc[4][16];
    #pragma unroll
    for (int i = 0; i < 4; ++i)
        #pragma unroll
        for (int l = 0; l < 16; ++l) acc[i][l] = 0.f;

    const int cnt = gcnt[c];
    const int nch = (cnt + 31) >> 5;
    for (int ch = 0; ch < nch; ++ch) {
        __syncthreads();
        if (t < 32) {
            int gi = ch * 32 + t;
            sh_gid[t] = (gi < cnt) ? gidx[c * GS + gi] : -1;
        }
        __syncthreads();
        #pragma unroll 4
        for (int jj = 0; jj < 32; ++jj) {
            int g = sh_gid[jj];
            sh_w[jj][t] = (g >= 0) ? W1[g * NH + t] : 0.f;
        }
        {
            int j  = t & 31;
            int rb2 = (t >> 5) * 8;
            int g  = sh_gid[j];
            #pragma unroll
            for (int ii = 0; ii < 8; ++ii)
                sh_x[rb2 + ii][j] = (g >= 0) ? X[(size_t)(row0 + rb2 + ii) * NG + g] : 0.f;
        }
        __syncthreads();
        #pragma unroll 8
        for (int j = 0; j < 32; ++j) {
            float xv[4];
            #pragma unroll
            for (int i = 0; i < 4; ++i) xv[i] = sh_x[ty * 4 + i][j];
            #pragma unroll
            for (int l = 0; l < 16; ++l) {
                float wv = sh_w[j][l * 16 + tx];
                #pragma unroll
                for (int i = 0; i < 4; ++i) acc[i][l] = fmaf(xv[i], wv, acc[i][l]);
            }
        }
    }
    #pragma unroll
    for (int i = 0; i < 4; ++i)
        #pragma unroll
        for (int l = 0; l < 16; ++l) {
            int col = l * 16 + tx;
            float v = acc[i][l] + b1[col];
            sh_big[ty * 4 + i][col] = (v >= 0.f) ? v : 0.01f * v;
        }

    float acc2[4][16];
    #pragma unroll
    for (int i = 0; i < 4; ++i)
        #pragma unroll
        for (int l = 0; l < 16; ++l) acc2[i][l] = 0.f;
    for (int ch = 0; ch < NH / 32; ++ch) {
        __syncthreads();
        #pragma unroll 4
        for (int jj = 0; jj < 32; ++jj)
            sh_w[jj][t] = W2[(size_t)(ch * 32 + jj) * NH + t];
        __syncthreads();
        #pragma unroll 8
        for (int j = 0; j < 32; ++j) {
            float xv[4];
            #pragma unroll
            for (int i = 0; i < 4; ++i) xv[i] = sh_big[ty * 4 + i][ch * 32 + j];
            #pragma unroll
            for (int l = 0; l < 16; ++l) {
                float wv = sh_w[j][l * 16 + tx];
                #pragma unroll
                for (int i = 0; i < 4; ++i) acc2[i][l] = fmaf(xv[i], wv, acc2[i][l]);
            }
        }
    }
    __syncthreads();
    #pragma unroll
    for (int i = 0; i < 4; ++i)
        #pragma unroll
        for (int l = 0; l < 16; ++l) {
            int col = l * 16 + tx;
            float v = acc2[i][l] + b2[col];
            sh_big[ty * 4 + i][col] = (v >= 0.f) ? v : 0.01f * v;
        }
    #pragma unroll 4
    for (int o = 0; o < NZD; ++o)
        sh_w[o][t] = cw[((size_t)c * NZD + o) * NH + t];
    __syncthreads();
    {
        int o  = t & 31;
        int rg = t >> 5;
        float cbv = cb[c * NZD + o];
        float zv[8];
        #pragma unroll
        for (int i = 0; i < 8; ++i) zv[i] = cbv;
        for (int h = 0; h < NH; ++h) {
            float wv = sh_w[o][h];
            #pragma unroll
            for (int i = 0; i < 8; ++i)
                zv[i] = fmaf(sh_big[rg * 8 + i][h], wv, zv[i]);
        }
        #pragma unroll
        for (int i = 0; i < 8; ++i) sh_x[rg * 8 + i][o] = zv[i];
    }
    __syncthreads();
    float* proto_s = &sh_w[0][0];
    float* i2e_s   = proto_s + NK * NP * NZD;
    float* cbias_s = i2e_s + NK * NP;
    for (int i = t; i < NK * NP * NZD; i += 256)
        proto_s[i] = protos[(size_t)c * NK * NP * NZD + i];
    if (t < NK * NP) i2e_s[t] = 0.5f * expf(-logvar[c * NK * NP + t]);
    if (t < NK)      cbias_s[t] = c_bias[c * NK + t];
    __syncthreads();
    for (int task = t; task < 64 * NK; task += 256) {
        int r = task / NK;
        int k = task - r * NK;
        float best = 3.4e38f;
        #pragma unroll
        for (int p = 0; p < NP; ++p) {
            float d2 = 0.f;
            const float* ppr = proto_s + (k * NP + p) * NZD;
            #pragma unroll
            for (int o = 0; o < NZD; ++o) {
                float dv = sh_x[r][o] - ppr[o];
                d2 = fmaf(dv, dv, d2);
            }
            float sc = d2 * i2e_s[k * NP + p];
            best = fminf(best, sc);
        }
        out_cl[((size_t)(row0 + r) * NC + c) * NK + k] = cbias_s[k] - best;
    }
}

// ---------------- logits reduce ---------------------------------------------
__global__ void reduce_logits(const float* __restrict__ cl,
                              const float* __restrict__ importance,
                              const float* __restrict__ bias,
                              float* __restrict__ out) {
    int idx = blockIdx.x * blockDim.x + threadIdx.x;
    if (idx >= NB * NK) return;
    int b = idx / NK;
    int k = idx - b * NK;
    float s = 0.f;
    #pragma unroll
    for (int c = 0; c < NC; ++c) {
        float imp = fabsf(importance[c]);
        s += expf(cl[((size_t)b * NC + c) * NK + k]) * imp + 1e-16f;
    }
    out[idx] = logf(s) + bias[k];
}

extern "C" void kernel_launch(void* const* d_in, const int* in_sizes, int n_in,
                              void* d_out, int out_size, void* d_ws, size_t ws_size,
                              hipStream_t stream) {
    const float* X      = (const float*)d_in[0];
    const float* M      = (const float*)d_in[1];
    const float* W1     = (const float*)d_in[2];
    const float* b1     = (const float*)d_in[3];
    const float* W2     = (const float*)d_in[4];
    const float* b2     = (const float*)d_in[5];
    const float* cw     = (const float*)d_in[6];
    const float* cb     = (const float*)d_in[7];
    const float* protos = (const float*)d_in[8];
    const float* logvar = (const float*)d_in[9];
    const float* c_bias = (const float*)d_in[10];
    const float* bias   = (const float*)d_in[11];
    const float* imp    = (const float*)d_in[12];

    float* out_logits = (float*)d_out;
    float* out_cl     = out_logits + NB * NK;

    // workspace layout (bytes)
    const size_t o_gcnt = (size_t)NC * GS * 4;
    const size_t o_w1s  = o_gcnt + 256;
    const size_t o_w2s  = o_w1s + (size_t)NC * NCH * 256 * 32 * 2;
    const size_t o_cwb  = o_w2s + (size_t)8 * 256 * 32 * 2;
    const size_t o_xt   = o_cwb + (size_t)NC * 32 * 256 * 2;
    const size_t need   = o_xt + (size_t)NG * NB * 2;

    int* gidx = (int*)d_ws;
    int* gcnt = (int*)((char*)d_ws + o_gcnt);
    unsigned short* w1s = (unsigned short*)((char*)d_ws + o_w1s);
    unsigned short* w2s = (unsigned short*)((char*)d_ws + o_w2s);
    unsigned short* cwb = (unsigned short*)((char*)d_ws + o_cwb);
    unsigned short* xt  = (unsigned short*)((char*)d_ws + o_xt);

    if (ws_size >= need) {
        prep_all<<<1582, 256, 0, stream>>>(X, W1, W2, cw, M, gidx, gcnt,
                                           xt, w1s, w2s, cwb);
        fused_mfma14<<<dim3(NB / BT, NC), 512, LDS_BYTES, stream>>>(
            xt, w1s, w2s, cwb, b1, b2, cb, protos, logvar, c_bias, gidx, gcnt, out_cl);
    } else {
        build_gidx<<<NC, 1024, 0, stream>>>(M, gidx, gcnt);
        size_t smem = (size_t)(16512 + 8256 + 2112) * 4 + 32 * 4;
        fused_main<<<dim3(NB / 64, NC), 256, smem, stream>>>(
            X, W1, b1, W2, b2, cw, cb, protos, logvar, c_bias, gidx, gcnt, out_cl);
    }
    reduce_logits<<<(NB * NK + 255) / 256, 256, 0, stream>>>(out_cl, imp, bias, out_logits);
}